// Round 1
// baseline (2179.367 us; speedup 1.0000x reference)
//
#include <hip/hip_runtime.h>
#include <hip/hip_bf16.h>
#include <stdint.h>

#define T_SEQ 32
#define BATCH 128
#define EMB   512
#define HID   1024
#define VOC   32000
#define G3    (3 * HID)            // 3072
#define MROWS (T_SEQ * BATCH)      // 4096

typedef __bf16 bf16_t;
typedef __bf16 bf16x8 __attribute__((ext_vector_type(8)));
typedef float  f32x4  __attribute__((ext_vector_type(4)));

// ---------------------------------------------------------------------------
// f32 -> bf16 conversion (vectorized)
// ---------------------------------------------------------------------------
__global__ void f32_to_bf16_kernel(const float* __restrict__ in,
                                   bf16_t* __restrict__ out, int n) {
    int i = (blockIdx.x * blockDim.x + threadIdx.x) * 4;
    if (i + 3 < n) {
        float4 v = *(const float4*)(in + i);
        out[i + 0] = (bf16_t)v.x;
        out[i + 1] = (bf16_t)v.y;
        out[i + 2] = (bf16_t)v.z;
        out[i + 3] = (bf16_t)v.w;
    } else {
        for (; i < n; ++i) out[i] = (bf16_t)in[i];
    }
}

// ---------------------------------------------------------------------------
// Embedding gather: X[t*B+b][:] = bf16(emb[tok(b,t)][:])
// tok(b,0) = 1 (SOS), tok(b,t) = x[b][t] for t>=1
// grid = 4096 blocks, block = 128 threads (each thread 4 cols)
// ---------------------------------------------------------------------------
__global__ void embed_kernel(const int* __restrict__ x,
                             const float* __restrict__ emb,
                             bf16_t* __restrict__ X) {
    int m = blockIdx.x;            // 0..4095
    int t = m >> 7, b = m & 127;
    int tok = (t == 0) ? 1 : x[b * T_SEQ + t];
    const float* src = emb + (size_t)tok * EMB;
    bf16_t* dst = X + (size_t)m * EMB;
    int c = threadIdx.x * 4;       // 128 threads * 4 = 512
    float4 v = *(const float4*)(src + c);
    dst[c + 0] = (bf16_t)v.x;
    dst[c + 1] = (bf16_t)v.y;
    dst[c + 2] = (bf16_t)v.z;
    dst[c + 3] = (bf16_t)v.w;
}

// ---------------------------------------------------------------------------
// GEMM: C[M,N] = A[M,K] * B[N,K]^T (+ bias[n])
// A, B bf16 row-major (K contiguous), C f32.
// Tile 128x128, 256 threads = 4 waves (2x2), each wave 64x64 via 4x4 16x16
// MFMA fragments. K-step 32, global_load_lds width-16 staging.
// Requires M%128==0 (grid.y = M/128), N%128==0, K%32==0.
// ---------------------------------------------------------------------------
#define GLOAD_LDS16(g, l)                                                    \
    __builtin_amdgcn_global_load_lds(                                        \
        (const __attribute__((address_space(1))) void*)(g),                  \
        (__attribute__((address_space(3))) void*)(l), 16, 0, 0)

template <int BIAS>
__global__ __launch_bounds__(256) void gemm_bf16_kernel(
    const bf16_t* __restrict__ A, const bf16_t* __restrict__ B,
    const float* __restrict__ bias, float* __restrict__ C,
    int M, int N, int K) {
    __shared__ __align__(16) bf16_t As[128 * 32];
    __shared__ __align__(16) bf16_t Bs[128 * 32];

    const int bm = blockIdx.y * 128;
    const int bn = blockIdx.x * 128;
    const int tid  = threadIdx.x;
    const int lane = tid & 63;
    const int w    = tid >> 6;
    const int wr   = w >> 1, wc = w & 1;

    f32x4 acc[4][4] = {};

    // staging addresses: thread tid loads 8 bf16 (16B); lds offset = tid*16B
    const int lrow = tid >> 2;          // 0..63
    const int lcol = (tid & 3) * 8;     // 0,8,16,24
    const bf16_t* ag = A + (size_t)(bm + lrow) * K + lcol;
    const bf16_t* bg = B + (size_t)(bn + lrow) * K + lcol;
    bf16_t* asl0 = As + lrow * 32 + lcol;
    bf16_t* asl1 = As + (lrow + 64) * 32 + lcol;
    bf16_t* bsl0 = Bs + lrow * 32 + lcol;
    bf16_t* bsl1 = Bs + (lrow + 64) * 32 + lcol;

    const int r16 = lane & 15;
    const int kh  = (lane >> 4) * 8;

    for (int k0 = 0; k0 < K; k0 += 32) {
        GLOAD_LDS16(ag + k0, asl0);
        GLOAD_LDS16(ag + (size_t)64 * K + k0, asl1);
        GLOAD_LDS16(bg + k0, bsl0);
        GLOAD_LDS16(bg + (size_t)64 * K + k0, bsl1);
        __syncthreads();

        bf16x8 af[4], bf[4];
#pragma unroll
        for (int mi = 0; mi < 4; ++mi)
            af[mi] = *(const bf16x8*)(As + (wr * 64 + mi * 16 + r16) * 32 + kh);
#pragma unroll
        for (int ni = 0; ni < 4; ++ni)
            bf[ni] = *(const bf16x8*)(Bs + (wc * 64 + ni * 16 + r16) * 32 + kh);
#pragma unroll
        for (int mi = 0; mi < 4; ++mi)
#pragma unroll
            for (int ni = 0; ni < 4; ++ni)
                acc[mi][ni] = __builtin_amdgcn_mfma_f32_16x16x32_bf16(
                    af[mi], bf[ni], acc[mi][ni], 0, 0, 0);
        __syncthreads();
    }

    // epilogue: D col = lane&15, row = (lane>>4)*4 + r
#pragma unroll
    for (int mi = 0; mi < 4; ++mi) {
        const int row0 = bm + wr * 64 + mi * 16 + (lane >> 4) * 4;
#pragma unroll
        for (int ni = 0; ni < 4; ++ni) {
            const int col = bn + wc * 64 + ni * 16 + r16;
            float bv = 0.f;
            if (BIAS) bv = bias[col];
#pragma unroll
            for (int r = 0; r < 4; ++r)
                C[(size_t)(row0 + r) * N + col] = acc[mi][ni][r] + bv;
        }
    }
}

// ---------------------------------------------------------------------------
// GRU gate fusion for one timestep (one layer):
//   r = sigmoid(ir+hr); z = sigmoid(iz+hz); n = tanh(in + r*hn)
//   h = (1-z)*n + z*h_prev
// Gi: [4096,3072] (indexed by t), gh: [128,3072], hprev: [128,1024] f32
// writes h f32 and bf16. grid = 512 blocks x 256 thr (131072 elems)
// ---------------------------------------------------------------------------
__global__ void gru_gate_kernel(const float* __restrict__ Gi,
                                const float* __restrict__ gh,
                                const float* __restrict__ hprev,
                                float* __restrict__ hout_f32,
                                bf16_t* __restrict__ hout_b16, int t) {
    int idx = blockIdx.x * blockDim.x + threadIdx.x;  // 0..131071
    int b = idx >> 10, j = idx & 1023;
    size_t gib = (size_t)(t * BATCH + b) * G3;
    float ir = Gi[gib + j];
    float iz = Gi[gib + HID + j];
    float in_ = Gi[gib + 2 * HID + j];
    size_t ghb = (size_t)b * G3;
    float hr = gh[ghb + j];
    float hz = gh[ghb + HID + j];
    float hn = gh[ghb + 2 * HID + j];
    float hp = hprev[idx];
    float r = 1.f / (1.f + __expf(-(ir + hr)));
    float z = 1.f / (1.f + __expf(-(iz + hz)));
    float n = tanhf(in_ + r * hn);
    float h = (1.f - z) * n + z * hp;
    hout_f32[idx] = h;
    hout_b16[idx] = (bf16_t)h;
}

// ---------------------------------------------------------------------------
extern "C" void kernel_launch(void* const* d_in, const int* in_sizes, int n_in,
                              void* d_out, int out_size, void* d_ws, size_t ws_size,
                              hipStream_t stream) {
    const int*   x        = (const int*)d_in[0];
    const float* enc_hid  = (const float*)d_in[2];   // [2,128,1024]
    const float* emb      = (const float*)d_in[3];
    const float* w_ih0    = (const float*)d_in[4];
    const float* w_hh0    = (const float*)d_in[5];
    const float* b_ih0    = (const float*)d_in[6];
    const float* b_hh0    = (const float*)d_in[7];
    const float* w_ih1    = (const float*)d_in[8];
    const float* w_hh1    = (const float*)d_in[9];
    const float* b_ih1    = (const float*)d_in[10];
    const float* b_hh1    = (const float*)d_in[11];
    const float* w_dec    = (const float*)d_in[12];
    const float* b_dec    = (const float*)d_in[13];
    float* out = (float*)d_out;

    char* ws = (char*)d_ws;
    size_t off = 0;
    auto alloc = [&](size_t bytes) {
        void* p = ws + off;
        off += (bytes + 255) & ~(size_t)255;
        return p;
    };
    bf16_t* Xb     = (bf16_t*)alloc((size_t)MROWS * EMB * 2);
    bf16_t* Wih0b  = (bf16_t*)alloc((size_t)G3 * EMB * 2);
    bf16_t* Whh0b  = (bf16_t*)alloc((size_t)G3 * HID * 2);
    bf16_t* Wih1b  = (bf16_t*)alloc((size_t)G3 * HID * 2);
    bf16_t* Whh1b  = (bf16_t*)alloc((size_t)G3 * HID * 2);
    bf16_t* Wdecb  = (bf16_t*)alloc((size_t)VOC * HID * 2);
    bf16_t* h0ib   = (bf16_t*)alloc((size_t)BATCH * HID * 2);
    bf16_t* h1ib   = (bf16_t*)alloc((size_t)BATCH * HID * 2);
    float*  Gi     = (float*)alloc((size_t)MROWS * G3 * 4);
    float*  gh     = (float*)alloc((size_t)BATCH * G3 * 4);
    float*  H0f    = (float*)alloc((size_t)MROWS * HID * 4);
    bf16_t* H0b    = (bf16_t*)alloc((size_t)MROWS * HID * 2);
    float*  H1f    = (float*)alloc((size_t)MROWS * HID * 4);
    bf16_t* H1b    = (bf16_t*)alloc((size_t)MROWS * HID * 2);

    auto cvt = [&](const float* src, bf16_t* dst, int n) {
        int blocks = (n + 1023) / 1024;
        f32_to_bf16_kernel<<<blocks, 256, 0, stream>>>(src, dst, n);
    };

    // weight + init conversions
    cvt(w_ih0, Wih0b, G3 * EMB);
    cvt(w_hh0, Whh0b, G3 * HID);
    cvt(w_ih1, Wih1b, G3 * HID);
    cvt(w_hh1, Whh1b, G3 * HID);
    cvt(w_dec, Wdecb, VOC * HID);
    cvt(enc_hid, h0ib, BATCH * HID);
    cvt(enc_hid + BATCH * HID, h1ib, BATCH * HID);

    // embedding gather
    embed_kernel<<<MROWS, 128, 0, stream>>>(x, emb, Xb);

    // Gi0 = X @ w_ih0^T + b_ih0  -> [4096, 3072]
    gemm_bf16_kernel<1><<<dim3(G3 / 128, MROWS / 128), 256, 0, stream>>>(
        Xb, Wih0b, b_ih0, Gi, MROWS, G3, EMB);

    // layer 0 scan
    for (int t = 0; t < T_SEQ; ++t) {
        const bf16_t* hb = (t == 0) ? h0ib : H0b + (size_t)(t - 1) * BATCH * HID;
        gemm_bf16_kernel<1><<<dim3(G3 / 128, 1), 256, 0, stream>>>(
            hb, Whh0b, b_hh0, gh, BATCH, G3, HID);
        const float* hp = (t == 0) ? enc_hid : H0f + (size_t)(t - 1) * BATCH * HID;
        gru_gate_kernel<<<512, 256, 0, stream>>>(
            Gi, gh, hp, H0f + (size_t)t * BATCH * HID,
            H0b + (size_t)t * BATCH * HID, t);
    }

    // Gi1 = H0 @ w_ih1^T + b_ih1 -> [4096, 3072] (reuse Gi)
    gemm_bf16_kernel<1><<<dim3(G3 / 128, MROWS / 128), 256, 0, stream>>>(
        H0b, Wih1b, b_ih1, Gi, MROWS, G3, HID);

    // layer 1 scan
    for (int t = 0; t < T_SEQ; ++t) {
        const bf16_t* hb = (t == 0) ? h1ib : H1b + (size_t)(t - 1) * BATCH * HID;
        gemm_bf16_kernel<1><<<dim3(G3 / 128, 1), 256, 0, stream>>>(
            hb, Whh1b, b_hh1, gh, BATCH, G3, HID);
        const float* hp = (t == 0) ? enc_hid + BATCH * HID
                                   : H1f + (size_t)(t - 1) * BATCH * HID;
        gru_gate_kernel<<<512, 256, 0, stream>>>(
            Gi, gh, hp, H1f + (size_t)t * BATCH * HID,
            H1b + (size_t)t * BATCH * HID, t);
    }

    // logits = H1 @ w_dec^T + b_dec -> [4096, 32000]
    gemm_bf16_kernel<1><<<dim3(VOC / 128, MROWS / 128), 256, 0, stream>>>(
        H1b, Wdecb, b_dec, out, MROWS, VOC, HID);
}

// Round 2
// 1995.649 us; speedup vs baseline: 1.0921x; 1.0921x over previous
//
#include <hip/hip_runtime.h>
#include <hip/hip_bf16.h>
#include <stdint.h>

#define T_SEQ 32
#define BATCH 128
#define EMB   512
#define HID   1024
#define VOC   32000
#define G3    (3 * HID)            // 3072
#define MROWS (T_SEQ * BATCH)      // 4096

typedef __bf16 bf16_t;
typedef __bf16 bf16x8 __attribute__((ext_vector_type(8)));
typedef float  f32x4  __attribute__((ext_vector_type(4)));

// ---------------------------------------------------------------------------
// f32 -> bf16 conversion (vectorized)
// ---------------------------------------------------------------------------
__global__ void f32_to_bf16_kernel(const float* __restrict__ in,
                                   bf16_t* __restrict__ out, int n) {
    int i = (blockIdx.x * blockDim.x + threadIdx.x) * 4;
    if (i + 3 < n) {
        float4 v = *(const float4*)(in + i);
        out[i + 0] = (bf16_t)v.x;
        out[i + 1] = (bf16_t)v.y;
        out[i + 2] = (bf16_t)v.z;
        out[i + 3] = (bf16_t)v.w;
    } else {
        for (; i < n; ++i) out[i] = (bf16_t)in[i];
    }
}

// ---------------------------------------------------------------------------
// Embedding gather: X[t*B+b][:] = bf16(emb[tok(b,t)][:])
// ---------------------------------------------------------------------------
__global__ void embed_kernel(const int* __restrict__ x,
                             const float* __restrict__ emb,
                             bf16_t* __restrict__ X) {
    int m = blockIdx.x;            // 0..4095
    int t = m >> 7, b = m & 127;
    int tok = (t == 0) ? 1 : x[b * T_SEQ + t];
    const float* src = emb + (size_t)tok * EMB;
    bf16_t* dst = X + (size_t)m * EMB;
    int c = threadIdx.x * 4;       // 128 threads * 4 = 512
    float4 v = *(const float4*)(src + c);
    dst[c + 0] = (bf16_t)v.x;
    dst[c + 1] = (bf16_t)v.y;
    dst[c + 2] = (bf16_t)v.z;
    dst[c + 3] = (bf16_t)v.w;
}

// ---------------------------------------------------------------------------
#define GLOAD_LDS16(g, l)                                                    \
    __builtin_amdgcn_global_load_lds(                                        \
        (const __attribute__((address_space(1))) void*)(g),                  \
        (__attribute__((address_space(3))) void*)(l), 16, 0, 0)

// ---------------------------------------------------------------------------
// GEMM: C[M,N] = A[M,K] * B[N,K]^T (+ bias[n]); bf16 in, f32 out.
// 128x128 tile, 4 waves, 16x16x32 MFMA, global_load_lds staging.
// XCD-aware bijective block swizzle; post-swizzle ids iterate bm fastest so
// one XCD chunk reuses a single 128-col B panel (L2-resident) across row tiles.
// ---------------------------------------------------------------------------
template <int BIAS>
__global__ __launch_bounds__(256) void gemm_bf16_kernel(
    const bf16_t* __restrict__ A, const bf16_t* __restrict__ B,
    const float* __restrict__ bias, float* __restrict__ C,
    int M, int N, int K) {
    __shared__ __align__(16) bf16_t As[128 * 32];
    __shared__ __align__(16) bf16_t Bs[128 * 32];

    const int nbm = gridDim.y, nbn = gridDim.x;
    const int nwg = nbm * nbn;
    int lin = blockIdx.y * nbn + blockIdx.x;
    if ((nwg & 7) == 0) {
        // bijective XCD swizzle: chunk nwg/8 consecutive ids per XCD
        int xcd = lin & 7, idx = lin >> 3;
        lin = xcd * (nwg >> 3) + idx;
    }
    const int bm = (lin % nbm) * 128;   // bm fastest: same B-panel reused
    const int bn = (lin / nbm) * 128;

    const int tid  = threadIdx.x;
    const int lane = tid & 63;
    const int w    = tid >> 6;
    const int wr   = w >> 1, wc = w & 1;

    f32x4 acc[4][4] = {};

    const int lrow = tid >> 2;          // 0..63
    const int lcol = (tid & 3) * 8;     // 0,8,16,24
    const bf16_t* ag = A + (size_t)(bm + lrow) * K + lcol;
    const bf16_t* bg = B + (size_t)(bn + lrow) * K + lcol;
    bf16_t* asl0 = As + lrow * 32 + lcol;
    bf16_t* asl1 = As + (lrow + 64) * 32 + lcol;
    bf16_t* bsl0 = Bs + lrow * 32 + lcol;
    bf16_t* bsl1 = Bs + (lrow + 64) * 32 + lcol;

    const int r16 = lane & 15;
    const int kh  = (lane >> 4) * 8;

    for (int k0 = 0; k0 < K; k0 += 32) {
        GLOAD_LDS16(ag + k0, asl0);
        GLOAD_LDS16(ag + (size_t)64 * K + k0, asl1);
        GLOAD_LDS16(bg + k0, bsl0);
        GLOAD_LDS16(bg + (size_t)64 * K + k0, bsl1);
        __syncthreads();

        bf16x8 af[4], bf[4];
#pragma unroll
        for (int mi = 0; mi < 4; ++mi)
            af[mi] = *(const bf16x8*)(As + (wr * 64 + mi * 16 + r16) * 32 + kh);
#pragma unroll
        for (int ni = 0; ni < 4; ++ni)
            bf[ni] = *(const bf16x8*)(Bs + (wc * 64 + ni * 16 + r16) * 32 + kh);
#pragma unroll
        for (int mi = 0; mi < 4; ++mi)
#pragma unroll
            for (int ni = 0; ni < 4; ++ni)
                acc[mi][ni] = __builtin_amdgcn_mfma_f32_16x16x32_bf16(
                    af[mi], bf[ni], acc[mi][ni], 0, 0, 0);
        __syncthreads();
    }

#pragma unroll
    for (int mi = 0; mi < 4; ++mi) {
        const int row0 = bm + wr * 64 + mi * 16 + (lane >> 4) * 4;
#pragma unroll
        for (int ni = 0; ni < 4; ++ni) {
            const int col = bn + wc * 64 + ni * 16 + r16;
            float bv = 0.f;
            if (BIAS) bv = bias[col];
#pragma unroll
            for (int r = 0; r < 4; ++r)
                C[(size_t)(row0 + r) * N + col] = acc[mi][ni][r] + bv;
        }
    }
}

// ---------------------------------------------------------------------------
// Fused GRU cell: gh = hprev @ w_hh^T, then gate math + h write, one launch.
// Block: H-column slice of 32 (c0), computes 3 gate tiles [128 x 32] (K=1024)
// so the nonlinearity is a pure epilogue. grid = 32 blocks x 256 thr (4 waves,
// wave w owns rows [32w, 32w+32)).
// Gi[(t*128+row)*3072 + g*1024 + c] already contains x-side + b_ih.
// ---------------------------------------------------------------------------
__global__ __launch_bounds__(256) void gru_cell_kernel(
    const bf16_t* __restrict__ hprev_b, const float* __restrict__ hprev_f,
    const bf16_t* __restrict__ whh, const float* __restrict__ bhh,
    const float* __restrict__ Gi, float* __restrict__ hout_f,
    bf16_t* __restrict__ hout_b, int t) {
    __shared__ __align__(16) bf16_t Hs[128 * 32];
    __shared__ __align__(16) bf16_t Ws[96 * 32];

    const int c0   = blockIdx.x * 32;
    const int tid  = threadIdx.x;
    const int lane = tid & 63;
    const int w    = tid >> 6;

    f32x4 acc[3][2][2] = {};

    const int lrow = tid >> 2;          // 0..63
    const int lk   = (tid & 3) * 8;
    const bf16_t* hg0 = hprev_b + (size_t)lrow * HID + lk;
    const bf16_t* hg1 = hprev_b + (size_t)(lrow + 64) * HID + lk;
    bf16_t* hs0 = Hs + lrow * 32 + lk;
    bf16_t* hs1 = Hs + (lrow + 64) * 32 + lk;
    // Ws rows 0..63: gates 0,1 (rows g*32 + (r&31)); rows 64..95: gate 2
    const int g0 = lrow >> 5;
    const bf16_t* wgp0 = whh + (size_t)(g0 * HID + c0 + (lrow & 31)) * HID + lk;
    bf16_t* ws0 = Ws + lrow * 32 + lk;
    const bf16_t* wgp1 = whh + (size_t)(2 * HID + c0 + (lrow & 31)) * HID + lk;
    bf16_t* ws1 = Ws + (64 + lrow) * 32 + lk;

    const int r16 = lane & 15;
    const int kh  = (lane >> 4) * 8;

    for (int k0 = 0; k0 < HID; k0 += 32) {
        GLOAD_LDS16(hg0 + k0, hs0);
        GLOAD_LDS16(hg1 + k0, hs1);
        GLOAD_LDS16(wgp0 + k0, ws0);
        if (tid < 128) GLOAD_LDS16(wgp1 + k0, ws1);
        __syncthreads();

        bf16x8 af[2], bfr[3][2];
#pragma unroll
        for (int mi = 0; mi < 2; ++mi)
            af[mi] = *(const bf16x8*)(Hs + (w * 32 + mi * 16 + r16) * 32 + kh);
#pragma unroll
        for (int g = 0; g < 3; ++g)
#pragma unroll
            for (int ni = 0; ni < 2; ++ni)
                bfr[g][ni] = *(const bf16x8*)(Ws + (g * 32 + ni * 16 + r16) * 32 + kh);
#pragma unroll
        for (int g = 0; g < 3; ++g)
#pragma unroll
            for (int mi = 0; mi < 2; ++mi)
#pragma unroll
                for (int ni = 0; ni < 2; ++ni)
                    acc[g][mi][ni] = __builtin_amdgcn_mfma_f32_16x16x32_bf16(
                        af[mi], bfr[g][ni], acc[g][mi][ni], 0, 0, 0);
        __syncthreads();
    }

    // epilogue: gate math. D frag: col=lane&15, row=(lane>>4)*4+r
#pragma unroll
    for (int mi = 0; mi < 2; ++mi) {
        const int row0 = w * 32 + mi * 16 + (lane >> 4) * 4;
#pragma unroll
        for (int ni = 0; ni < 2; ++ni) {
            const int ch = c0 + ni * 16 + r16;
            const float bh_r = bhh[ch];
            const float bh_z = bhh[HID + ch];
            const float bh_n = bhh[2 * HID + ch];
#pragma unroll
            for (int r = 0; r < 4; ++r) {
                const int row = row0 + r;
                const size_t gib = (size_t)(t * BATCH + row) * G3;
                float gi_r = Gi[gib + ch];
                float gi_z = Gi[gib + HID + ch];
                float gi_n = Gi[gib + 2 * HID + ch];
                float hp   = hprev_f[(size_t)row * HID + ch];
                float rr = 1.f / (1.f + __expf(-(gi_r + acc[0][mi][ni][r] + bh_r)));
                float zz = 1.f / (1.f + __expf(-(gi_z + acc[1][mi][ni][r] + bh_z)));
                float hn = acc[2][mi][ni][r] + bh_n;
                float nn = tanhf(gi_n + rr * hn);
                float h  = (1.f - zz) * nn + zz * hp;
                hout_f[(size_t)row * HID + ch] = h;
                hout_b[(size_t)row * HID + ch] = (bf16_t)h;
            }
        }
    }
}

// ---------------------------------------------------------------------------
extern "C" void kernel_launch(void* const* d_in, const int* in_sizes, int n_in,
                              void* d_out, int out_size, void* d_ws, size_t ws_size,
                              hipStream_t stream) {
    const int*   x        = (const int*)d_in[0];
    const float* enc_hid  = (const float*)d_in[2];   // [2,128,1024]
    const float* emb      = (const float*)d_in[3];
    const float* w_ih0    = (const float*)d_in[4];
    const float* w_hh0    = (const float*)d_in[5];
    const float* b_ih0    = (const float*)d_in[6];
    const float* b_hh0    = (const float*)d_in[7];
    const float* w_ih1    = (const float*)d_in[8];
    const float* w_hh1    = (const float*)d_in[9];
    const float* b_ih1    = (const float*)d_in[10];
    const float* b_hh1    = (const float*)d_in[11];
    const float* w_dec    = (const float*)d_in[12];
    const float* b_dec    = (const float*)d_in[13];
    float* out = (float*)d_out;

    char* ws = (char*)d_ws;
    size_t off = 0;
    auto alloc = [&](size_t bytes) {
        void* p = ws + off;
        off += (bytes + 255) & ~(size_t)255;
        return p;
    };
    bf16_t* Xb     = (bf16_t*)alloc((size_t)MROWS * EMB * 2);
    bf16_t* Wih0b  = (bf16_t*)alloc((size_t)G3 * EMB * 2);
    bf16_t* Whh0b  = (bf16_t*)alloc((size_t)G3 * HID * 2);
    bf16_t* Wih1b  = (bf16_t*)alloc((size_t)G3 * HID * 2);
    bf16_t* Whh1b  = (bf16_t*)alloc((size_t)G3 * HID * 2);
    bf16_t* Wdecb  = (bf16_t*)alloc((size_t)VOC * HID * 2);
    bf16_t* h0ib   = (bf16_t*)alloc((size_t)BATCH * HID * 2);
    bf16_t* h1ib   = (bf16_t*)alloc((size_t)BATCH * HID * 2);
    float*  Gi     = (float*)alloc((size_t)MROWS * G3 * 4);
    float*  H0f    = (float*)alloc((size_t)MROWS * HID * 4);
    bf16_t* H0b    = (bf16_t*)alloc((size_t)MROWS * HID * 2);
    float*  H1f    = (float*)alloc((size_t)MROWS * HID * 4);
    bf16_t* H1b    = (bf16_t*)alloc((size_t)MROWS * HID * 2);

    auto cvt = [&](const float* src, bf16_t* dst, int n) {
        int blocks = (n + 1023) / 1024;
        f32_to_bf16_kernel<<<blocks, 256, 0, stream>>>(src, dst, n);
    };

    cvt(w_ih0, Wih0b, G3 * EMB);
    cvt(w_hh0, Whh0b, G3 * HID);
    cvt(w_ih1, Wih1b, G3 * HID);
    cvt(w_hh1, Whh1b, G3 * HID);
    cvt(w_dec, Wdecb, VOC * HID);
    cvt(enc_hid, h0ib, BATCH * HID);
    cvt(enc_hid + BATCH * HID, h1ib, BATCH * HID);

    embed_kernel<<<MROWS, 128, 0, stream>>>(x, emb, Xb);

    // Gi0 = X @ w_ih0^T + b_ih0  -> [4096, 3072]
    gemm_bf16_kernel<1><<<dim3(G3 / 128, MROWS / 128), 256, 0, stream>>>(
        Xb, Wih0b, b_ih0, Gi, MROWS, G3, EMB);

    // layer 0 scan: fused cell per step
    for (int t = 0; t < T_SEQ; ++t) {
        const bf16_t* hb = (t == 0) ? h0ib : H0b + (size_t)(t - 1) * BATCH * HID;
        const float*  hf = (t == 0) ? enc_hid : H0f + (size_t)(t - 1) * BATCH * HID;
        gru_cell_kernel<<<32, 256, 0, stream>>>(
            hb, hf, Whh0b, b_hh0, Gi,
            H0f + (size_t)t * BATCH * HID, H0b + (size_t)t * BATCH * HID, t);
    }

    // Gi1 = H0 @ w_ih1^T + b_ih1 -> [4096, 3072]
    gemm_bf16_kernel<1><<<dim3(G3 / 128, MROWS / 128), 256, 0, stream>>>(
        H0b, Wih1b, b_ih1, Gi, MROWS, G3, HID);

    // layer 1 scan
    for (int t = 0; t < T_SEQ; ++t) {
        const bf16_t* hb = (t == 0) ? h1ib : H1b + (size_t)(t - 1) * BATCH * HID;
        const float*  hf = (t == 0) ? enc_hid + BATCH * HID
                                    : H1f + (size_t)(t - 1) * BATCH * HID;
        gru_cell_kernel<<<32, 256, 0, stream>>>(
            hb, hf, Whh1b, b_hh1, Gi,
            H1f + (size_t)t * BATCH * HID, H1b + (size_t)t * BATCH * HID, t);
    }

    // logits = H1 @ w_dec^T + b_dec -> [4096, 32000]
    gemm_bf16_kernel<1><<<dim3(VOC / 128, MROWS / 128), 256, 0, stream>>>(
        H1b, Wdecb, b_dec, out, MROWS, VOC, HID);
}

// Round 3
// 1929.265 us; speedup vs baseline: 1.1296x; 1.0344x over previous
//
#include <hip/hip_runtime.h>
#include <hip/hip_bf16.h>
#include <stdint.h>

#define T_SEQ 32
#define BATCH 128
#define EMB   512
#define HID   1024
#define VOC   32000
#define G3    (3 * HID)            // 3072
#define MROWS (T_SEQ * BATCH)      // 4096
#define NBLK  64                   // persistent-kernel grid (16 cols each)

typedef __bf16 bf16_t;
typedef __bf16 bf16x8 __attribute__((ext_vector_type(8)));
typedef float  f32x4  __attribute__((ext_vector_type(4)));

// ---------------------------------------------------------------------------
// f32 -> bf16 conversion (vectorized)
// ---------------------------------------------------------------------------
__global__ void f32_to_bf16_kernel(const float* __restrict__ in,
                                   bf16_t* __restrict__ out, int n) {
    int i = (blockIdx.x * blockDim.x + threadIdx.x) * 4;
    if (i + 3 < n) {
        float4 v = *(const float4*)(in + i);
        out[i + 0] = (bf16_t)v.x;
        out[i + 1] = (bf16_t)v.y;
        out[i + 2] = (bf16_t)v.z;
        out[i + 3] = (bf16_t)v.w;
    } else {
        for (; i < n; ++i) out[i] = (bf16_t)in[i];
    }
}

// ---------------------------------------------------------------------------
// Embedding gather
// ---------------------------------------------------------------------------
__global__ void embed_kernel(const int* __restrict__ x,
                             const float* __restrict__ emb,
                             bf16_t* __restrict__ X) {
    int m = blockIdx.x;            // 0..4095
    int t = m >> 7, b = m & 127;
    int tok = (t == 0) ? 1 : x[b * T_SEQ + t];
    const float* src = emb + (size_t)tok * EMB;
    bf16_t* dst = X + (size_t)m * EMB;
    int c = threadIdx.x * 4;
    float4 v = *(const float4*)(src + c);
    dst[c + 0] = (bf16_t)v.x;
    dst[c + 1] = (bf16_t)v.y;
    dst[c + 2] = (bf16_t)v.z;
    dst[c + 3] = (bf16_t)v.w;
}

// ---------------------------------------------------------------------------
#define GLOAD_LDS16(g, l)                                                    \
    __builtin_amdgcn_global_load_lds(                                        \
        (const __attribute__((address_space(1))) void*)(g),                  \
        (__attribute__((address_space(3))) void*)(l), 16, 0, 0)

// ---------------------------------------------------------------------------
// GEMM: C[M,N] = A[M,K]*B[N,K]^T (+bias). 128x128 tile, 4 waves, bf16 MFMA.
// ---------------------------------------------------------------------------
template <int BIAS>
__global__ __launch_bounds__(256) void gemm_bf16_kernel(
    const bf16_t* __restrict__ A, const bf16_t* __restrict__ B,
    const float* __restrict__ bias, float* __restrict__ C,
    int M, int N, int K) {
    __shared__ __align__(16) bf16_t As[128 * 32];
    __shared__ __align__(16) bf16_t Bs[128 * 32];

    const int nbm = gridDim.y, nbn = gridDim.x;
    const int nwg = nbm * nbn;
    int lin = blockIdx.y * nbn + blockIdx.x;
    if ((nwg & 7) == 0) {
        int xcd = lin & 7, idx = lin >> 3;
        lin = xcd * (nwg >> 3) + idx;
    }
    const int bm = (lin % nbm) * 128;
    const int bn = (lin / nbm) * 128;

    const int tid  = threadIdx.x;
    const int lane = tid & 63;
    const int w    = tid >> 6;
    const int wr   = w >> 1, wc = w & 1;

    f32x4 acc[4][4] = {};

    const int lrow = tid >> 2;
    const int lcol = (tid & 3) * 8;
    const bf16_t* ag = A + (size_t)(bm + lrow) * K + lcol;
    const bf16_t* bg = B + (size_t)(bn + lrow) * K + lcol;
    bf16_t* asl0 = As + lrow * 32 + lcol;
    bf16_t* asl1 = As + (lrow + 64) * 32 + lcol;
    bf16_t* bsl0 = Bs + lrow * 32 + lcol;
    bf16_t* bsl1 = Bs + (lrow + 64) * 32 + lcol;

    const int r16 = lane & 15;
    const int kh  = (lane >> 4) * 8;

    for (int k0 = 0; k0 < K; k0 += 32) {
        GLOAD_LDS16(ag + k0, asl0);
        GLOAD_LDS16(ag + (size_t)64 * K + k0, asl1);
        GLOAD_LDS16(bg + k0, bsl0);
        GLOAD_LDS16(bg + (size_t)64 * K + k0, bsl1);
        __syncthreads();

        bf16x8 af[4], bf[4];
#pragma unroll
        for (int mi = 0; mi < 4; ++mi)
            af[mi] = *(const bf16x8*)(As + (wr * 64 + mi * 16 + r16) * 32 + kh);
#pragma unroll
        for (int ni = 0; ni < 4; ++ni)
            bf[ni] = *(const bf16x8*)(Bs + (wc * 64 + ni * 16 + r16) * 32 + kh);
#pragma unroll
        for (int mi = 0; mi < 4; ++mi)
#pragma unroll
            for (int ni = 0; ni < 4; ++ni)
                acc[mi][ni] = __builtin_amdgcn_mfma_f32_16x16x32_bf16(
                    af[mi], bf[ni], acc[mi][ni], 0, 0, 0);
        __syncthreads();
    }

#pragma unroll
    for (int mi = 0; mi < 4; ++mi) {
        const int row0 = bm + wr * 64 + mi * 16 + (lane >> 4) * 4;
#pragma unroll
        for (int ni = 0; ni < 4; ++ni) {
            const int col = bn + wc * 64 + ni * 16 + r16;
            float bv = 0.f;
            if (BIAS) bv = bias[col];
#pragma unroll
            for (int r = 0; r < 4; ++r)
                C[(size_t)(row0 + r) * N + col] = acc[mi][ni][r] + bv;
        }
    }
}

// ---------------------------------------------------------------------------
// Persistent GRU layer kernel: all 32 timesteps in one launch.
// Grid: 64 blocks x 256 threads. Block owns H-cols [c0, c0+16) for all 3
// gates. Wave w owns k-slice [w*256,(w+1)*256): weight B-frags stationary in
// VGPRs (loaded once), h_prev A-frags loaded global->reg each step (its own
// 64KB slice; each h byte read once per block). Cross-wave k-reduction + gate
// math via LDS, then device-scope spin barrier between timesteps.
// ---------------------------------------------------------------------------
__device__ __forceinline__ void gsync(unsigned* cnt, unsigned target) {
    __threadfence();
    __syncthreads();
    if (threadIdx.x == 0) {
        __hip_atomic_fetch_add(cnt, 1u, __ATOMIC_ACQ_REL,
                               __HIP_MEMORY_SCOPE_AGENT);
        while (__hip_atomic_load(cnt, __ATOMIC_ACQUIRE,
                                 __HIP_MEMORY_SCOPE_AGENT) < target) {}
        __threadfence();
    }
    __syncthreads();
}

__global__ __launch_bounds__(256, 1) void gru_layer_kernel(
    const bf16_t* __restrict__ h0b, const float* __restrict__ h0f,
    const bf16_t* __restrict__ whh, const float* __restrict__ bhh,
    const float* __restrict__ Gi, float* __restrict__ Hf,
    bf16_t* __restrict__ Hb, unsigned* __restrict__ cnt) {
    __shared__ float Sg[4][3][128][16];   // 96 KB: [kslice][gate][row][col]

    const int tid  = threadIdx.x;
    const int lane = tid & 63;
    const int w    = tid >> 6;          // k-slice owner
    const int c0   = blockIdx.x * 16;
    const int r16  = lane & 15;
    const int kq   = (lane >> 4) * 8;   // k sub-offset within 32-frag

    // stationary weights: wf[g][kf] covers cols c0..c0+15, k = w*256+kf*32
    bf16x8 wf[3][8];
#pragma unroll
    for (int g = 0; g < 3; ++g)
#pragma unroll
        for (int kf = 0; kf < 8; ++kf)
            wf[g][kf] = *(const bf16x8*)(
                whh + (size_t)(g * HID + c0 + r16) * HID + w * 256 + kf * 32 + kq);

    for (int t = 0; t < T_SEQ; ++t) {
        const bf16_t* hb = t ? Hb + (size_t)(t - 1) * BATCH * HID : h0b;
        const float*  hf = t ? Hf + (size_t)(t - 1) * BATCH * HID : h0f;

        f32x4 acc[3][8] = {};
#pragma unroll
        for (int kf = 0; kf < 8; ++kf) {
            const int kbase = w * 256 + kf * 32 + kq;
            bf16x8 af[8];
#pragma unroll
            for (int rf = 0; rf < 8; ++rf)
                af[rf] = *(const bf16x8*)(hb + (size_t)(rf * 16 + r16) * HID + kbase);
#pragma unroll
            for (int rf = 0; rf < 8; ++rf) {
                acc[0][rf] = __builtin_amdgcn_mfma_f32_16x16x32_bf16(
                    af[rf], wf[0][kf], acc[0][rf], 0, 0, 0);
                acc[1][rf] = __builtin_amdgcn_mfma_f32_16x16x32_bf16(
                    af[rf], wf[1][kf], acc[1][rf], 0, 0, 0);
                acc[2][rf] = __builtin_amdgcn_mfma_f32_16x16x32_bf16(
                    af[rf], wf[2][kf], acc[2][rf], 0, 0, 0);
            }
        }

        // partials to LDS: D frag col = lane&15, row = rf*16 + (lane>>4)*4 + r
#pragma unroll
        for (int g = 0; g < 3; ++g)
#pragma unroll
            for (int rf = 0; rf < 8; ++rf)
#pragma unroll
                for (int r = 0; r < 4; ++r)
                    Sg[w][g][rf * 16 + (lane >> 4) * 4 + r][r16] = acc[g][rf][r];
        __syncthreads();

        // epilogue: thread -> col = tid&15, rows (tid>>4)*8 .. +8
        {
            const int col = tid & 15;
            const int ch  = c0 + col;
            const int row0 = (tid >> 4) * 8;
            const float bh_r = bhh[ch];
            const float bh_z = bhh[HID + ch];
            const float bh_n = bhh[2 * HID + ch];
#pragma unroll
            for (int i = 0; i < 8; ++i) {
                const int row = row0 + i;
                float gr = Sg[0][0][row][col] + Sg[1][0][row][col] +
                           Sg[2][0][row][col] + Sg[3][0][row][col];
                float gz = Sg[0][1][row][col] + Sg[1][1][row][col] +
                           Sg[2][1][row][col] + Sg[3][1][row][col];
                float gn = Sg[0][2][row][col] + Sg[1][2][row][col] +
                           Sg[2][2][row][col] + Sg[3][2][row][col];
                const size_t gib = (size_t)(t * BATCH + row) * G3;
                float gi_r = Gi[gib + ch];
                float gi_z = Gi[gib + HID + ch];
                float gi_n = Gi[gib + 2 * HID + ch];
                float hp   = hf[(size_t)row * HID + ch];
                float rr = 1.f / (1.f + __expf(-(gi_r + gr + bh_r)));
                float zz = 1.f / (1.f + __expf(-(gi_z + gz + bh_z)));
                float nn = tanhf(gi_n + rr * (gn + bh_n));
                float h  = (1.f - zz) * nn + zz * hp;
                Hf[(size_t)t * BATCH * HID + (size_t)row * HID + ch] = h;
                Hb[(size_t)t * BATCH * HID + (size_t)row * HID + ch] = (bf16_t)h;
            }
        }

        if (t < T_SEQ - 1)
            gsync(cnt, (unsigned)(NBLK * (t + 1)));
    }
}

// ---------------------------------------------------------------------------
extern "C" void kernel_launch(void* const* d_in, const int* in_sizes, int n_in,
                              void* d_out, int out_size, void* d_ws, size_t ws_size,
                              hipStream_t stream) {
    const int*   x        = (const int*)d_in[0];
    const float* enc_hid  = (const float*)d_in[2];   // [2,128,1024]
    const float* emb      = (const float*)d_in[3];
    const float* w_ih0    = (const float*)d_in[4];
    const float* w_hh0    = (const float*)d_in[5];
    const float* b_ih0    = (const float*)d_in[6];
    const float* b_hh0    = (const float*)d_in[7];
    const float* w_ih1    = (const float*)d_in[8];
    const float* w_hh1    = (const float*)d_in[9];
    const float* b_ih1    = (const float*)d_in[10];
    const float* b_hh1    = (const float*)d_in[11];
    const float* w_dec    = (const float*)d_in[12];
    const float* b_dec    = (const float*)d_in[13];
    float* out = (float*)d_out;

    char* ws = (char*)d_ws;
    size_t off = 0;
    auto alloc = [&](size_t bytes) {
        void* p = ws + off;
        off += (bytes + 255) & ~(size_t)255;
        return p;
    };
    unsigned* cnts = (unsigned*)alloc(256);          // [0]: layer0, [16]: layer1
    bf16_t* Xb     = (bf16_t*)alloc((size_t)MROWS * EMB * 2);
    bf16_t* Wih0b  = (bf16_t*)alloc((size_t)G3 * EMB * 2);
    bf16_t* Whh0b  = (bf16_t*)alloc((size_t)G3 * HID * 2);
    bf16_t* Wih1b  = (bf16_t*)alloc((size_t)G3 * HID * 2);
    bf16_t* Whh1b  = (bf16_t*)alloc((size_t)G3 * HID * 2);
    bf16_t* Wdecb  = (bf16_t*)alloc((size_t)VOC * HID * 2);
    bf16_t* h0ib   = (bf16_t*)alloc((size_t)BATCH * HID * 2);
    bf16_t* h1ib   = (bf16_t*)alloc((size_t)BATCH * HID * 2);
    float*  Gi     = (float*)alloc((size_t)MROWS * G3 * 4);
    float*  H0f    = (float*)alloc((size_t)MROWS * HID * 4);
    bf16_t* H0b    = (bf16_t*)alloc((size_t)MROWS * HID * 2);
    float*  H1f    = (float*)alloc((size_t)MROWS * HID * 4);
    bf16_t* H1b    = (bf16_t*)alloc((size_t)MROWS * HID * 2);

    hipMemsetAsync(cnts, 0, 256, stream);

    auto cvt = [&](const float* src, bf16_t* dst, int n) {
        int blocks = (n + 1023) / 1024;
        f32_to_bf16_kernel<<<blocks, 256, 0, stream>>>(src, dst, n);
    };

    cvt(w_ih0, Wih0b, G3 * EMB);
    cvt(w_hh0, Whh0b, G3 * HID);
    cvt(w_ih1, Wih1b, G3 * HID);
    cvt(w_hh1, Whh1b, G3 * HID);
    cvt(w_dec, Wdecb, VOC * HID);
    cvt(enc_hid, h0ib, BATCH * HID);
    cvt(enc_hid + BATCH * HID, h1ib, BATCH * HID);

    embed_kernel<<<MROWS, 128, 0, stream>>>(x, emb, Xb);

    // Gi0 = X @ w_ih0^T + b_ih0  -> [4096, 3072]
    gemm_bf16_kernel<1><<<dim3(G3 / 128, MROWS / 128), 256, 0, stream>>>(
        Xb, Wih0b, b_ih0, Gi, MROWS, G3, EMB);

    // layer 0: persistent scan
    gru_layer_kernel<<<NBLK, 256, 0, stream>>>(
        h0ib, enc_hid, Whh0b, b_hh0, Gi, H0f, H0b, cnts);

    // Gi1 = H0 @ w_ih1^T + b_ih1 -> [4096, 3072]
    gemm_bf16_kernel<1><<<dim3(G3 / 128, MROWS / 128), 256, 0, stream>>>(
        H0b, Wih1b, b_ih1, Gi, MROWS, G3, HID);

    // layer 1: persistent scan
    gru_layer_kernel<<<NBLK, 256, 0, stream>>>(
        h1ib, enc_hid + BATCH * HID, Whh1b, b_hh1, Gi, H1f, H1b, cnts + 16);

    // logits = H1 @ w_dec^T + b_dec -> [4096, 32000]
    gemm_bf16_kernel<1><<<dim3(VOC / 128, MROWS / 128), 256, 0, stream>>>(
        H1b, Wdecb, b_dec, out, MROWS, VOC, HID);
}

// Round 4
// 1535.886 us; speedup vs baseline: 1.4190x; 1.2561x over previous
//
#include <hip/hip_runtime.h>
#include <hip/hip_bf16.h>
#include <stdint.h>

#define T_SEQ 32
#define BATCH 128
#define EMB   512
#define HID   1024
#define VOC   32000
#define G3    (3 * HID)            // 3072
#define MROWS (T_SEQ * BATCH)      // 4096
#define NBLK  64                   // persistent-kernel grid (16 cols each)
#define BHID  (BATCH * HID)

typedef __bf16 bf16_t;
typedef __bf16 bf16x8 __attribute__((ext_vector_type(8)));
typedef __bf16 bf16x4 __attribute__((ext_vector_type(4)));
typedef float  f32x4  __attribute__((ext_vector_type(4)));

// ---------------------------------------------------------------------------
// f32 -> bf16 conversion (vectorized)
// ---------------------------------------------------------------------------
__global__ void f32_to_bf16_kernel(const float* __restrict__ in,
                                   bf16_t* __restrict__ out, int n) {
    int i = (blockIdx.x * blockDim.x + threadIdx.x) * 4;
    if (i + 3 < n) {
        float4 v = *(const float4*)(in + i);
        out[i + 0] = (bf16_t)v.x;
        out[i + 1] = (bf16_t)v.y;
        out[i + 2] = (bf16_t)v.z;
        out[i + 3] = (bf16_t)v.w;
    } else {
        for (; i < n; ++i) out[i] = (bf16_t)in[i];
    }
}

// ---------------------------------------------------------------------------
// Embedding gather
// ---------------------------------------------------------------------------
__global__ void embed_kernel(const int* __restrict__ x,
                             const float* __restrict__ emb,
                             bf16_t* __restrict__ X) {
    int m = blockIdx.x;            // 0..4095
    int t = m >> 7, b = m & 127;
    int tok = (t == 0) ? 1 : x[b * T_SEQ + t];
    const float* src = emb + (size_t)tok * EMB;
    bf16_t* dst = X + (size_t)m * EMB;
    int c = threadIdx.x * 4;
    float4 v = *(const float4*)(src + c);
    dst[c + 0] = (bf16_t)v.x;
    dst[c + 1] = (bf16_t)v.y;
    dst[c + 2] = (bf16_t)v.z;
    dst[c + 3] = (bf16_t)v.w;
}

// ---------------------------------------------------------------------------
#define GLOAD_LDS16(g, l)                                                    \
    __builtin_amdgcn_global_load_lds(                                        \
        (const __attribute__((address_space(1))) void*)(g),                  \
        (__attribute__((address_space(3))) void*)(l), 16, 0, 0)

// ---------------------------------------------------------------------------
// GEMM: C[M,N] = A[M,K]*B[N,K]^T (+bias). 128x128 tile, 4 waves, bf16 MFMA.
// (unchanged from R2/R3 — frozen while the recurrence is optimized)
// ---------------------------------------------------------------------------
template <int BIAS>
__global__ __launch_bounds__(256) void gemm_bf16_kernel(
    const bf16_t* __restrict__ A, const bf16_t* __restrict__ B,
    const float* __restrict__ bias, float* __restrict__ C,
    int M, int N, int K) {
    __shared__ __align__(16) bf16_t As[128 * 32];
    __shared__ __align__(16) bf16_t Bs[128 * 32];

    const int nbm = gridDim.y, nbn = gridDim.x;
    const int nwg = nbm * nbn;
    int lin = blockIdx.y * nbn + blockIdx.x;
    if ((nwg & 7) == 0) {
        int xcd = lin & 7, idx = lin >> 3;
        lin = xcd * (nwg >> 3) + idx;
    }
    const int bm = (lin % nbm) * 128;
    const int bn = (lin / nbm) * 128;

    const int tid  = threadIdx.x;
    const int lane = tid & 63;
    const int w    = tid >> 6;
    const int wr   = w >> 1, wc = w & 1;

    f32x4 acc[4][4] = {};

    const int lrow = tid >> 2;
    const int lcol = (tid & 3) * 8;
    const bf16_t* ag = A + (size_t)(bm + lrow) * K + lcol;
    const bf16_t* bg = B + (size_t)(bn + lrow) * K + lcol;
    bf16_t* asl0 = As + lrow * 32 + lcol;
    bf16_t* asl1 = As + (lrow + 64) * 32 + lcol;
    bf16_t* bsl0 = Bs + lrow * 32 + lcol;
    bf16_t* bsl1 = Bs + (lrow + 64) * 32 + lcol;

    const int r16 = lane & 15;
    const int kh  = (lane >> 4) * 8;

    for (int k0 = 0; k0 < K; k0 += 32) {
        GLOAD_LDS16(ag + k0, asl0);
        GLOAD_LDS16(ag + (size_t)64 * K + k0, asl1);
        GLOAD_LDS16(bg + k0, bsl0);
        GLOAD_LDS16(bg + (size_t)64 * K + k0, bsl1);
        __syncthreads();

        bf16x8 af[4], bf[4];
#pragma unroll
        for (int mi = 0; mi < 4; ++mi)
            af[mi] = *(const bf16x8*)(As + (wr * 64 + mi * 16 + r16) * 32 + kh);
#pragma unroll
        for (int ni = 0; ni < 4; ++ni)
            bf[ni] = *(const bf16x8*)(Bs + (wc * 64 + ni * 16 + r16) * 32 + kh);
#pragma unroll
        for (int mi = 0; mi < 4; ++mi)
#pragma unroll
            for (int ni = 0; ni < 4; ++ni)
                acc[mi][ni] = __builtin_amdgcn_mfma_f32_16x16x32_bf16(
                    af[mi], bf[ni], acc[mi][ni], 0, 0, 0);
        __syncthreads();
    }

#pragma unroll
    for (int mi = 0; mi < 4; ++mi) {
        const int row0 = bm + wr * 64 + mi * 16 + (lane >> 4) * 4;
#pragma unroll
        for (int ni = 0; ni < 4; ++ni) {
            const int col = bn + wc * 64 + ni * 16 + r16;
            float bv = 0.f;
            if (BIAS) bv = bias[col];
#pragma unroll
            for (int r = 0; r < 4; ++r)
                C[(size_t)(row0 + r) * N + col] = acc[mi][ni][r] + bv;
        }
    }
}

// ---------------------------------------------------------------------------
// Persistent GRU layer kernel, v2.
// 64 blocks x 256 thr; block owns 16 H-cols; wave w owns k-slice [w*256,+256)
// with stationary weight frags in VGPRs. Changes vs v1:
//  - flag-array barrier (release store to own line; wave0 polls 64 flags)
//  - Gi[t+1] prefetched into regs before the barrier
//  - h carried bf16-only; epilogue's h_prev carried in registers
//  - epilogue thread = 4 cols x 2 rows, vectorized f32x4/bf16x4
//  - double-buffered af loads (2 kf in flight)
// ---------------------------------------------------------------------------
__global__ __launch_bounds__(256, 1) void gru_layer_kernel(
    const bf16_t* __restrict__ h0b, const float* __restrict__ h0f,
    const bf16_t* __restrict__ whh, const float* __restrict__ bhh,
    const float* __restrict__ Gi, bf16_t* __restrict__ Hb,
    unsigned* __restrict__ flags) {
    __shared__ __align__(16) float Sg[4][3][128][16];   // 96 KB

    const int tid  = threadIdx.x;
    const int lane = tid & 63;
    const int w    = tid >> 6;          // k-slice owner
    const int bid  = blockIdx.x;
    const int c0   = bid * 16;
    const int r16  = lane & 15;
    const int kq   = (lane >> 4) * 8;   // k sub-offset within 32-frag

    // stationary weights: wf[g][kf] covers cols c0..c0+15, k = w*256+kf*32
    bf16x8 wf[3][8];
#pragma unroll
    for (int g = 0; g < 3; ++g)
#pragma unroll
        for (int kf = 0; kf < 8; ++kf)
            wf[g][kf] = *(const bf16x8*)(
                whh + (size_t)(g * HID + c0 + r16) * HID + w * 256 + kf * 32 + kq);

    // epilogue ownership: 4 cols x 2 rows per thread
    const int cg   = tid & 3;           // col group (4 cols)
    const int rloc = tid >> 2;          // 0..63; rows rloc, rloc+64
    const int ce   = c0 + cg * 4;

    float bh[3][4];
#pragma unroll
    for (int g = 0; g < 3; ++g)
#pragma unroll
        for (int j = 0; j < 4; ++j) bh[g][j] = bhh[g * HID + ce + j];

    float hp[2][4];
    f32x4 gi[2][3];
#pragma unroll
    for (int i = 0; i < 2; ++i) {
        const int row = rloc + i * 64;
#pragma unroll
        for (int j = 0; j < 4; ++j)
            hp[i][j] = h0f[(size_t)row * HID + ce + j];
        const size_t gb = (size_t)row * G3 + ce;   // t = 0
        gi[i][0] = *(const f32x4*)(Gi + gb);
        gi[i][1] = *(const f32x4*)(Gi + gb + HID);
        gi[i][2] = *(const f32x4*)(Gi + gb + 2 * HID);
    }

    for (int t = 0; t < T_SEQ; ++t) {
        const bf16_t* hb = t ? Hb + (size_t)(t - 1) * BHID : h0b;

        // ---- MFMA phase: gh partials for k-slice w ----
        f32x4 acc[3][8] = {};
        bf16x8 afA[8], afB[8];
#define LD_AF(dst, kf)                                                       \
    {                                                                        \
        const int kbase = w * 256 + (kf) * 32 + kq;                          \
        _Pragma("unroll") for (int rf = 0; rf < 8; ++rf)                     \
            dst[rf] = *(const bf16x8*)(hb + (size_t)(rf * 16 + r16) * HID + kbase); \
    }
        LD_AF(afA, 0)
#pragma unroll
        for (int kf = 0; kf < 8; ++kf) {
            const bf16x8* cur = (kf & 1) ? afB : afA;
            if (kf < 7) {
                if (kf & 1) LD_AF(afA, kf + 1)
                else        LD_AF(afB, kf + 1)
            }
#pragma unroll
            for (int rf = 0; rf < 8; ++rf) {
                acc[0][rf] = __builtin_amdgcn_mfma_f32_16x16x32_bf16(
                    cur[rf], wf[0][kf], acc[0][rf], 0, 0, 0);
                acc[1][rf] = __builtin_amdgcn_mfma_f32_16x16x32_bf16(
                    cur[rf], wf[1][kf], acc[1][rf], 0, 0, 0);
                acc[2][rf] = __builtin_amdgcn_mfma_f32_16x16x32_bf16(
                    cur[rf], wf[2][kf], acc[2][rf], 0, 0, 0);
            }
        }
#undef LD_AF

        // partials to LDS: D frag col = lane&15, row = rf*16 + (lane>>4)*4 + r
#pragma unroll
        for (int g = 0; g < 3; ++g)
#pragma unroll
            for (int rf = 0; rf < 8; ++rf)
#pragma unroll
                for (int r = 0; r < 4; ++r)
                    Sg[w][g][rf * 16 + (lane >> 4) * 4 + r][r16] = acc[g][rf][r];
        __syncthreads();

        // ---- epilogue: k-reduce + gate math, 4 cols x 2 rows ----
#pragma unroll
        for (int i = 0; i < 2; ++i) {
            const int row = rloc + i * 64;
            f32x4 gr = *(const f32x4*)&Sg[0][0][row][cg * 4];
            f32x4 gz = *(const f32x4*)&Sg[0][1][row][cg * 4];
            f32x4 gn = *(const f32x4*)&Sg[0][2][row][cg * 4];
#pragma unroll
            for (int ks = 1; ks < 4; ++ks) {
                gr += *(const f32x4*)&Sg[ks][0][row][cg * 4];
                gz += *(const f32x4*)&Sg[ks][1][row][cg * 4];
                gn += *(const f32x4*)&Sg[ks][2][row][cg * 4];
            }
            bf16x4 hb4;
#pragma unroll
            for (int j = 0; j < 4; ++j) {
                float rr = 1.f / (1.f + __expf(-(gi[i][0][j] + gr[j] + bh[0][j])));
                float zz = 1.f / (1.f + __expf(-(gi[i][1][j] + gz[j] + bh[1][j])));
                float nn = tanhf(gi[i][2][j] + rr * (gn[j] + bh[2][j]));
                float h  = (1.f - zz) * nn + zz * hp[i][j];
                hp[i][j] = h;
                hb4[j]   = (bf16_t)h;
            }
            *(bf16x4*)(Hb + (size_t)t * BHID + (size_t)row * HID + ce) = hb4;
        }

        if (t < T_SEQ - 1) {
            // ---- publish h(t), prefetch Gi(t+1), wait for all blocks ----
            __syncthreads();   // all stores in block issued (+vmcnt drained)
            if (tid == 0)
                __hip_atomic_store(&flags[bid * 16], (unsigned)(t + 1),
                                   __ATOMIC_RELEASE, __HIP_MEMORY_SCOPE_AGENT);
#pragma unroll
            for (int i = 0; i < 2; ++i) {
                const size_t gb =
                    ((size_t)(t + 1) * BATCH + rloc + i * 64) * G3 + ce;
                gi[i][0] = *(const f32x4*)(Gi + gb);
                gi[i][1] = *(const f32x4*)(Gi + gb + HID);
                gi[i][2] = *(const f32x4*)(Gi + gb + 2 * HID);
            }
            if (tid < 64) {
                while (__hip_atomic_load(&flags[tid * 16], __ATOMIC_RELAXED,
                                         __HIP_MEMORY_SCOPE_AGENT) <
                       (unsigned)(t + 1))
                    __builtin_amdgcn_s_sleep(1);
            }
            __builtin_amdgcn_fence(__ATOMIC_ACQUIRE, "agent");
            __syncthreads();
        }
    }
}

// ---------------------------------------------------------------------------
extern "C" void kernel_launch(void* const* d_in, const int* in_sizes, int n_in,
                              void* d_out, int out_size, void* d_ws, size_t ws_size,
                              hipStream_t stream) {
    const int*   x        = (const int*)d_in[0];
    const float* enc_hid  = (const float*)d_in[2];   // [2,128,1024]
    const float* emb      = (const float*)d_in[3];
    const float* w_ih0    = (const float*)d_in[4];
    const float* w_hh0    = (const float*)d_in[5];
    const float* b_ih0    = (const float*)d_in[6];
    const float* b_hh0    = (const float*)d_in[7];
    const float* w_ih1    = (const float*)d_in[8];
    const float* w_hh1    = (const float*)d_in[9];
    const float* b_ih1    = (const float*)d_in[10];
    const float* b_hh1    = (const float*)d_in[11];
    const float* w_dec    = (const float*)d_in[12];
    const float* b_dec    = (const float*)d_in[13];
    float* out = (float*)d_out;

    char* ws = (char*)d_ws;
    size_t off = 0;
    auto alloc = [&](size_t bytes) {
        void* p = ws + off;
        off += (bytes + 255) & ~(size_t)255;
        return p;
    };
    unsigned* flags0 = (unsigned*)alloc(NBLK * 64);  // 64B-padded flags
    unsigned* flags1 = (unsigned*)alloc(NBLK * 64);
    bf16_t* Xb     = (bf16_t*)alloc((size_t)MROWS * EMB * 2);
    bf16_t* Wih0b  = (bf16_t*)alloc((size_t)G3 * EMB * 2);
    bf16_t* Whh0b  = (bf16_t*)alloc((size_t)G3 * HID * 2);
    bf16_t* Wih1b  = (bf16_t*)alloc((size_t)G3 * HID * 2);
    bf16_t* Whh1b  = (bf16_t*)alloc((size_t)G3 * HID * 2);
    bf16_t* Wdecb  = (bf16_t*)alloc((size_t)VOC * HID * 2);
    bf16_t* h0ib   = (bf16_t*)alloc((size_t)BATCH * HID * 2);
    bf16_t* h1ib   = (bf16_t*)alloc((size_t)BATCH * HID * 2);
    float*  Gi     = (float*)alloc((size_t)MROWS * G3 * 4);
    bf16_t* H0b    = (bf16_t*)alloc((size_t)MROWS * HID * 2);
    bf16_t* H1b    = (bf16_t*)alloc((size_t)MROWS * HID * 2);

    hipMemsetAsync(flags0, 0, NBLK * 64 * 2, stream);

    auto cvt = [&](const float* src, bf16_t* dst, int n) {
        int blocks = (n + 1023) / 1024;
        f32_to_bf16_kernel<<<blocks, 256, 0, stream>>>(src, dst, n);
    };

    cvt(w_ih0, Wih0b, G3 * EMB);
    cvt(w_hh0, Whh0b, G3 * HID);
    cvt(w_ih1, Wih1b, G3 * HID);
    cvt(w_hh1, Whh1b, G3 * HID);
    cvt(w_dec, Wdecb, VOC * HID);
    cvt(enc_hid, h0ib, BATCH * HID);
    cvt(enc_hid + BATCH * HID, h1ib, BATCH * HID);

    embed_kernel<<<MROWS, 128, 0, stream>>>(x, emb, Xb);

    // Gi0 = X @ w_ih0^T + b_ih0  -> [4096, 3072]
    gemm_bf16_kernel<1><<<dim3(G3 / 128, MROWS / 128), 256, 0, stream>>>(
        Xb, Wih0b, b_ih0, Gi, MROWS, G3, EMB);

    // layer 0: persistent scan
    gru_layer_kernel<<<NBLK, 256, 0, stream>>>(
        h0ib, enc_hid, Whh0b, b_hh0, Gi, H0b, flags0);

    // Gi1 = H0 @ w_ih1^T + b_ih1 -> [4096, 3072]
    gemm_bf16_kernel<1><<<dim3(G3 / 128, MROWS / 128), 256, 0, stream>>>(
        H0b, Wih1b, b_ih1, Gi, MROWS, G3, HID);

    // layer 1: persistent scan
    gru_layer_kernel<<<NBLK, 256, 0, stream>>>(
        h1ib, enc_hid + BATCH * HID, Whh1b, b_hh1, Gi, H1b, flags1);

    // logits = H1 @ w_dec^T + b_dec -> [4096, 32000]
    gemm_bf16_kernel<1><<<dim3(VOC / 128, MROWS / 128), 256, 0, stream>>>(
        H1b, Wdecb, b_dec, out, MROWS, VOC, HID);
}

// Round 5
// 1358.595 us; speedup vs baseline: 1.6041x; 1.1305x over previous
//
#include <hip/hip_runtime.h>
#include <hip/hip_bf16.h>
#include <stdint.h>

#define T_SEQ 32
#define BATCH 128
#define EMB   512
#define HID   1024
#define VOC   32000
#define G3    (3 * HID)            // 3072
#define MROWS (T_SEQ * BATCH)      // 4096
#define NBLK  64                   // persistent-kernel grid (16 cols each)
#define BHID  (BATCH * HID)

typedef __bf16 bf16_t;
typedef __bf16 bf16x8 __attribute__((ext_vector_type(8)));
typedef __bf16 bf16x4 __attribute__((ext_vector_type(4)));
typedef float  f32x4  __attribute__((ext_vector_type(4)));

// ---------------------------------------------------------------------------
// f32 -> bf16 conversion (vectorized)
// ---------------------------------------------------------------------------
__global__ void f32_to_bf16_kernel(const float* __restrict__ in,
                                   bf16_t* __restrict__ out, int n) {
    int i = (blockIdx.x * blockDim.x + threadIdx.x) * 4;
    if (i + 3 < n) {
        float4 v = *(const float4*)(in + i);
        out[i + 0] = (bf16_t)v.x;
        out[i + 1] = (bf16_t)v.y;
        out[i + 2] = (bf16_t)v.z;
        out[i + 3] = (bf16_t)v.w;
    } else {
        for (; i < n; ++i) out[i] = (bf16_t)in[i];
    }
}

// ---------------------------------------------------------------------------
// Embedding gather
// ---------------------------------------------------------------------------
__global__ void embed_kernel(const int* __restrict__ x,
                             const float* __restrict__ emb,
                             bf16_t* __restrict__ X) {
    int m = blockIdx.x;            // 0..4095
    int t = m >> 7, b = m & 127;
    int tok = (t == 0) ? 1 : x[b * T_SEQ + t];
    const float* src = emb + (size_t)tok * EMB;
    bf16_t* dst = X + (size_t)m * EMB;
    int c = threadIdx.x * 4;
    float4 v = *(const float4*)(src + c);
    dst[c + 0] = (bf16_t)v.x;
    dst[c + 1] = (bf16_t)v.y;
    dst[c + 2] = (bf16_t)v.z;
    dst[c + 3] = (bf16_t)v.w;
}

// ---------------------------------------------------------------------------
#define GLOAD_LDS16(g, l)                                                    \
    __builtin_amdgcn_global_load_lds(                                        \
        (const __attribute__((address_space(1))) void*)(g),                  \
        (__attribute__((address_space(3))) void*)(l), 16, 0, 0)

// ---------------------------------------------------------------------------
// GEMM: C[M,N] = A[M,K]*B[N,K]^T (+bias). 128x128 tile, 4 waves, bf16 MFMA.
// (frozen while the recurrence is optimized)
// ---------------------------------------------------------------------------
template <int BIAS>
__global__ __launch_bounds__(256) void gemm_bf16_kernel(
    const bf16_t* __restrict__ A, const bf16_t* __restrict__ B,
    const float* __restrict__ bias, float* __restrict__ C,
    int M, int N, int K) {
    __shared__ __align__(16) bf16_t As[128 * 32];
    __shared__ __align__(16) bf16_t Bs[128 * 32];

    const int nbm = gridDim.y, nbn = gridDim.x;
    const int nwg = nbm * nbn;
    int lin = blockIdx.y * nbn + blockIdx.x;
    if ((nwg & 7) == 0) {
        int xcd = lin & 7, idx = lin >> 3;
        lin = xcd * (nwg >> 3) + idx;
    }
    const int bm = (lin % nbm) * 128;
    const int bn = (lin / nbm) * 128;

    const int tid  = threadIdx.x;
    const int lane = tid & 63;
    const int w    = tid >> 6;
    const int wr   = w >> 1, wc = w & 1;

    f32x4 acc[4][4] = {};

    const int lrow = tid >> 2;
    const int lcol = (tid & 3) * 8;
    const bf16_t* ag = A + (size_t)(bm + lrow) * K + lcol;
    const bf16_t* bg = B + (size_t)(bn + lrow) * K + lcol;
    bf16_t* asl0 = As + lrow * 32 + lcol;
    bf16_t* asl1 = As + (lrow + 64) * 32 + lcol;
    bf16_t* bsl0 = Bs + lrow * 32 + lcol;
    bf16_t* bsl1 = Bs + (lrow + 64) * 32 + lcol;

    const int r16 = lane & 15;
    const int kh  = (lane >> 4) * 8;

    for (int k0 = 0; k0 < K; k0 += 32) {
        GLOAD_LDS16(ag + k0, asl0);
        GLOAD_LDS16(ag + (size_t)64 * K + k0, asl1);
        GLOAD_LDS16(bg + k0, bsl0);
        GLOAD_LDS16(bg + (size_t)64 * K + k0, bsl1);
        __syncthreads();

        bf16x8 af[4], bf[4];
#pragma unroll
        for (int mi = 0; mi < 4; ++mi)
            af[mi] = *(const bf16x8*)(As + (wr * 64 + mi * 16 + r16) * 32 + kh);
#pragma unroll
        for (int ni = 0; ni < 4; ++ni)
            bf[ni] = *(const bf16x8*)(Bs + (wc * 64 + ni * 16 + r16) * 32 + kh);
#pragma unroll
        for (int mi = 0; mi < 4; ++mi)
#pragma unroll
            for (int ni = 0; ni < 4; ++ni)
                acc[mi][ni] = __builtin_amdgcn_mfma_f32_16x16x32_bf16(
                    af[mi], bf[ni], acc[mi][ni], 0, 0, 0);
        __syncthreads();
    }

#pragma unroll
    for (int mi = 0; mi < 4; ++mi) {
        const int row0 = bm + wr * 64 + mi * 16 + (lane >> 4) * 4;
#pragma unroll
        for (int ni = 0; ni < 4; ++ni) {
            const int col = bn + wc * 64 + ni * 16 + r16;
            float bv = 0.f;
            if (BIAS) bv = bias[col];
#pragma unroll
            for (int r = 0; r < 4; ++r)
                C[(size_t)(row0 + r) * N + col] = acc[mi][ni][r] + bv;
        }
    }
}

// ---------------------------------------------------------------------------
// Persistent GRU layer kernel, v3.
// 64 blocks x 256 thr; block owns 16 H-cols; wave w owns k-slice [w*256,+256)
// with stationary weight frags in VGPRs. v3 changes:
//  - h exchange via fine-grained coherence: relaxed SYSTEM-scope atomics
//    (sc0 sc1: write-through to L3 / cache-bypassing reads). NO release/
//    acquire fences -> no per-step buffer_wbl2 / buffer_inv, L2 stays warm.
//  - packed 4B flags; wave0 polls all 64 with one coalesced sc-load
//  - 4-deep software-pipelined h fragment loads (24 outstanding)
// ---------------------------------------------------------------------------
union U64cast { bf16x4 v; unsigned long long u; };

__global__ __launch_bounds__(256, 1) void gru_layer_kernel(
    const bf16_t* __restrict__ h0b, const float* __restrict__ h0f,
    const bf16_t* __restrict__ whh, const float* __restrict__ bhh,
    const float* __restrict__ Gi, bf16_t* __restrict__ Hb,
    unsigned* __restrict__ flags) {
    __shared__ __align__(16) float Sg[4][3][128][16];   // 96 KB

    const int tid  = threadIdx.x;
    const int lane = tid & 63;
    const int w    = tid >> 6;          // k-slice owner
    const int bid  = blockIdx.x;
    const int c0   = bid * 16;
    const int r16  = lane & 15;
    const int kq   = (lane >> 4) * 8;   // k sub-offset within 32-frag

    // stationary weights: wf[g][kf] covers cols c0..c0+15, k = w*256+kf*32
    bf16x8 wf[3][8];
#pragma unroll
    for (int g = 0; g < 3; ++g)
#pragma unroll
        for (int kf = 0; kf < 8; ++kf)
            wf[g][kf] = *(const bf16x8*)(
                whh + (size_t)(g * HID + c0 + r16) * HID + w * 256 + kf * 32 + kq);

    // epilogue ownership: 4 cols x 2 rows per thread
    const int cg   = tid & 3;           // col group (4 cols)
    const int rloc = tid >> 2;          // 0..63; rows rloc, rloc+64
    const int ce   = c0 + cg * 4;

    float bh[3][4];
#pragma unroll
    for (int g = 0; g < 3; ++g)
#pragma unroll
        for (int j = 0; j < 4; ++j) bh[g][j] = bhh[g * HID + ce + j];

    float hp[2][4];
    f32x4 gi[2][3];
#pragma unroll
    for (int i = 0; i < 2; ++i) {
        const int row = rloc + i * 64;
#pragma unroll
        for (int j = 0; j < 4; ++j)
            hp[i][j] = h0f[(size_t)row * HID + ce + j];
        const size_t gb = (size_t)row * G3 + ce;   // t = 0
        gi[i][0] = *(const f32x4*)(Gi + gb);
        gi[i][1] = *(const f32x4*)(Gi + gb + HID);
        gi[i][2] = *(const f32x4*)(Gi + gb + 2 * HID);
    }

    for (int t = 0; t < T_SEQ; ++t) {
        const bf16_t* hb = t ? Hb + (size_t)(t - 1) * BHID : h0b;

        // ---- MFMA phase: gh partials for k-slice w, 4-deep load pipeline ----
        f32x4 acc[3][8] = {};
        bf16x8 af[4][8];
#define LD_GROUP(buf, kf)                                                    \
    {                                                                        \
        const int kbase = w * 256 + (kf) * 32 + kq;                          \
        _Pragma("unroll") for (int rf = 0; rf < 8; ++rf)                     \
            af[buf][rf] =                                                    \
                *(const bf16x8*)(hb + (size_t)(rf * 16 + r16) * HID + kbase); \
    }
        LD_GROUP(0, 0)
        LD_GROUP(1, 1)
        LD_GROUP(2, 2)
#pragma unroll
        for (int kf = 0; kf < 8; ++kf) {
            if (kf + 3 < 8) LD_GROUP((kf + 3) & 3, kf + 3)
#pragma unroll
            for (int rf = 0; rf < 8; ++rf) {
                acc[0][rf] = __builtin_amdgcn_mfma_f32_16x16x32_bf16(
                    af[kf & 3][rf], wf[0][kf], acc[0][rf], 0, 0, 0);
                acc[1][rf] = __builtin_amdgcn_mfma_f32_16x16x32_bf16(
                    af[kf & 3][rf], wf[1][kf], acc[1][rf], 0, 0, 0);
                acc[2][rf] = __builtin_amdgcn_mfma_f32_16x16x32_bf16(
                    af[kf & 3][rf], wf[2][kf], acc[2][rf], 0, 0, 0);
            }
        }
#undef LD_GROUP

        // partials to LDS: D frag col = lane&15, row = rf*16 + (lane>>4)*4 + r
#pragma unroll
        for (int g = 0; g < 3; ++g)
#pragma unroll
            for (int rf = 0; rf < 8; ++rf)
#pragma unroll
                for (int r = 0; r < 4; ++r)
                    Sg[w][g][rf * 16 + (lane >> 4) * 4 + r][r16] = acc[g][rf][r];
        __syncthreads();

        // ---- epilogue: k-reduce + gate math, 4 cols x 2 rows ----
#pragma unroll
        for (int i = 0; i < 2; ++i) {
            const int row = rloc + i * 64;
            f32x4 gr = *(const f32x4*)&Sg[0][0][row][cg * 4];
            f32x4 gz = *(const f32x4*)&Sg[0][1][row][cg * 4];
            f32x4 gn = *(const f32x4*)&Sg[0][2][row][cg * 4];
#pragma unroll
            for (int ks = 1; ks < 4; ++ks) {
                gr += *(const f32x4*)&Sg[ks][0][row][cg * 4];
                gz += *(const f32x4*)&Sg[ks][1][row][cg * 4];
                gn += *(const f32x4*)&Sg[ks][2][row][cg * 4];
            }
            U64cast hb4;
#pragma unroll
            for (int j = 0; j < 4; ++j) {
                float rr = 1.f / (1.f + __expf(-(gi[i][0][j] + gr[j] + bh[0][j])));
                float zz = 1.f / (1.f + __expf(-(gi[i][1][j] + gz[j] + bh[1][j])));
                float nn = tanhf(gi[i][2][j] + rr * (gn[j] + bh[2][j]));
                float h  = (1.f - zz) * nn + zz * hp[i][j];
                hp[i][j] = h;
                hb4.v[j] = (bf16_t)h;
            }
            // fine-grained (sc0 sc1) write-through store: visible at L3 once
            // this wave's vmcnt drains (no wbl2 needed)
            __hip_atomic_store(
                (unsigned long long*)(Hb + (size_t)t * BHID +
                                      (size_t)row * HID + ce),
                hb4.u, __ATOMIC_RELAXED, __HIP_MEMORY_SCOPE_SYSTEM);
        }

        if (t < T_SEQ - 1) {
            // publish h(t): syncthreads drains every wave's stores (vmcnt(0))
            __syncthreads();
            if (tid == 0)
                __hip_atomic_store(&flags[bid], (unsigned)(t + 1),
                                   __ATOMIC_RELAXED, __HIP_MEMORY_SCOPE_SYSTEM);
            // prefetch Gi(t+1) (plain loads, L2-warm) while waiting
#pragma unroll
            for (int i = 0; i < 2; ++i) {
                const size_t gb =
                    ((size_t)(t + 1) * BATCH + rloc + i * 64) * G3 + ce;
                gi[i][0] = *(const f32x4*)(Gi + gb);
                gi[i][1] = *(const f32x4*)(Gi + gb + HID);
                gi[i][2] = *(const f32x4*)(Gi + gb + 2 * HID);
            }
            if (tid < 64) {
                while (__hip_atomic_load(&flags[tid], __ATOMIC_RELAXED,
                                         __HIP_MEMORY_SCOPE_SYSTEM) <
                       (unsigned)(t + 1))
                    __builtin_amdgcn_s_sleep(1);
            }
            __syncthreads();
        }
    }
}

// ---------------------------------------------------------------------------
extern "C" void kernel_launch(void* const* d_in, const int* in_sizes, int n_in,
                              void* d_out, int out_size, void* d_ws, size_t ws_size,
                              hipStream_t stream) {
    const int*   x        = (const int*)d_in[0];
    const float* enc_hid  = (const float*)d_in[2];   // [2,128,1024]
    const float* emb      = (const float*)d_in[3];
    const float* w_ih0    = (const float*)d_in[4];
    const float* w_hh0    = (const float*)d_in[5];
    const float* b_ih0    = (const float*)d_in[6];
    const float* b_hh0    = (const float*)d_in[7];
    const float* w_ih1    = (const float*)d_in[8];
    const float* w_hh1    = (const float*)d_in[9];
    const float* b_ih1    = (const float*)d_in[10];
    const float* b_hh1    = (const float*)d_in[11];
    const float* w_dec    = (const float*)d_in[12];
    const float* b_dec    = (const float*)d_in[13];
    float* out = (float*)d_out;

    char* ws = (char*)d_ws;
    size_t off = 0;
    auto alloc = [&](size_t bytes) {
        void* p = ws + off;
        off += (bytes + 255) & ~(size_t)255;
        return p;
    };
    unsigned* flags0 = (unsigned*)alloc(NBLK * 4);   // packed 4B flags
    unsigned* flags1 = (unsigned*)alloc(NBLK * 4);
    bf16_t* Xb     = (bf16_t*)alloc((size_t)MROWS * EMB * 2);
    bf16_t* Wih0b  = (bf16_t*)alloc((size_t)G3 * EMB * 2);
    bf16_t* Whh0b  = (bf16_t*)alloc((size_t)G3 * HID * 2);
    bf16_t* Wih1b  = (bf16_t*)alloc((size_t)G3 * HID * 2);
    bf16_t* Whh1b  = (bf16_t*)alloc((size_t)G3 * HID * 2);
    bf16_t* Wdecb  = (bf16_t*)alloc((size_t)VOC * HID * 2);
    bf16_t* h0ib   = (bf16_t*)alloc((size_t)BATCH * HID * 2);
    bf16_t* h1ib   = (bf16_t*)alloc((size_t)BATCH * HID * 2);
    float*  Gi     = (float*)alloc((size_t)MROWS * G3 * 4);
    bf16_t* H0b    = (bf16_t*)alloc((size_t)MROWS * HID * 2);
    bf16_t* H1b    = (bf16_t*)alloc((size_t)MROWS * HID * 2);

    hipMemsetAsync(flags0, 0, 512, stream);   // covers flags0 + flags1

    auto cvt = [&](const float* src, bf16_t* dst, int n) {
        int blocks = (n + 1023) / 1024;
        f32_to_bf16_kernel<<<blocks, 256, 0, stream>>>(src, dst, n);
    };

    cvt(w_ih0, Wih0b, G3 * EMB);
    cvt(w_hh0, Whh0b, G3 * HID);
    cvt(w_ih1, Wih1b, G3 * HID);
    cvt(w_hh1, Whh1b, G3 * HID);
    cvt(w_dec, Wdecb, VOC * HID);
    cvt(enc_hid, h0ib, BATCH * HID);
    cvt(enc_hid + BATCH * HID, h1ib, BATCH * HID);

    embed_kernel<<<MROWS, 128, 0, stream>>>(x, emb, Xb);

    // Gi0 = X @ w_ih0^T + b_ih0  -> [4096, 3072]
    gemm_bf16_kernel<1><<<dim3(G3 / 128, MROWS / 128), 256, 0, stream>>>(
        Xb, Wih0b, b_ih0, Gi, MROWS, G3, EMB);

    // layer 0: persistent scan
    gru_layer_kernel<<<NBLK, 256, 0, stream>>>(
        h0ib, enc_hid, Whh0b, b_hh0, Gi, H0b, flags0);

    // Gi1 = H0 @ w_ih1^T + b_ih1 -> [4096, 3072]
    gemm_bf16_kernel<1><<<dim3(G3 / 128, MROWS / 128), 256, 0, stream>>>(
        H0b, Wih1b, b_ih1, Gi, MROWS, G3, HID);

    // layer 1: persistent scan
    gru_layer_kernel<<<NBLK, 256, 0, stream>>>(
        h1ib, enc_hid + BATCH * HID, Whh1b, b_hh1, Gi, H1b, flags1);

    // logits = H1 @ w_dec^T + b_dec -> [4096, 32000]
    gemm_bf16_kernel<1><<<dim3(VOC / 128, MROWS / 128), 256, 0, stream>>>(
        H1b, Wdecb, b_dec, out, MROWS, VOC, HID);
}

// Round 6
// 1250.856 us; speedup vs baseline: 1.7423x; 1.0861x over previous
//
#include <hip/hip_runtime.h>
#include <hip/hip_bf16.h>
#include <stdint.h>

#define T_SEQ 32
#define BATCH 128
#define EMB   512
#define HID   1024
#define VOC   32000
#define G3    (3 * HID)            // 3072
#define MROWS (T_SEQ * BATCH)      // 4096
#define NBLK  64                   // persistent-kernel grid (16 cols each)
#define BHID  (BATCH * HID)

typedef __bf16 bf16_t;
typedef __bf16 bf16x8 __attribute__((ext_vector_type(8)));
typedef __bf16 bf16x4 __attribute__((ext_vector_type(4)));
typedef float  f32x4  __attribute__((ext_vector_type(4)));

#define MFMA(a, b, c) __builtin_amdgcn_mfma_f32_16x16x32_bf16((a), (b), (c), 0, 0, 0)

// ---------------------------------------------------------------------------
// f32 -> bf16 conversion (vectorized)
// ---------------------------------------------------------------------------
__global__ void f32_to_bf16_kernel(const float* __restrict__ in,
                                   bf16_t* __restrict__ out, int n) {
    int i = (blockIdx.x * blockDim.x + threadIdx.x) * 4;
    if (i + 3 < n) {
        float4 v = *(const float4*)(in + i);
        out[i + 0] = (bf16_t)v.x;
        out[i + 1] = (bf16_t)v.y;
        out[i + 2] = (bf16_t)v.z;
        out[i + 3] = (bf16_t)v.w;
    } else {
        for (; i < n; ++i) out[i] = (bf16_t)in[i];
    }
}

// ---------------------------------------------------------------------------
// Embedding gather
// ---------------------------------------------------------------------------
__global__ void embed_kernel(const int* __restrict__ x,
                             const float* __restrict__ emb,
                             bf16_t* __restrict__ X) {
    int m = blockIdx.x;            // 0..4095
    int t = m >> 7, b = m & 127;
    int tok = (t == 0) ? 1 : x[b * T_SEQ + t];
    const float* src = emb + (size_t)tok * EMB;
    bf16_t* dst = X + (size_t)m * EMB;
    int c = threadIdx.x * 4;
    float4 v = *(const float4*)(src + c);
    dst[c + 0] = (bf16_t)v.x;
    dst[c + 1] = (bf16_t)v.y;
    dst[c + 2] = (bf16_t)v.z;
    dst[c + 3] = (bf16_t)v.w;
}

// ---------------------------------------------------------------------------
#define GLOAD_LDS16(g, l)                                                    \
    __builtin_amdgcn_global_load_lds(                                        \
        (const __attribute__((address_space(1))) void*)(g),                  \
        (__attribute__((address_space(3))) void*)(l), 16, 0, 0)

// ---------------------------------------------------------------------------
// GEMM 128x128 (m97 structure) — used for the Gi GEMMs (proven correct).
// ---------------------------------------------------------------------------
template <int BIAS>
__global__ __launch_bounds__(256) void gemm_bf16_kernel(
    const bf16_t* __restrict__ A, const bf16_t* __restrict__ B,
    const float* __restrict__ bias, float* __restrict__ C,
    int M, int N, int K) {
    __shared__ __align__(16) bf16_t As[128 * 32];
    __shared__ __align__(16) bf16_t Bs[128 * 32];

    const int nbm = gridDim.y, nbn = gridDim.x;
    const int nwg = nbm * nbn;
    int lin = blockIdx.y * nbn + blockIdx.x;
    if ((nwg & 7) == 0) {
        int xcd = lin & 7, idx = lin >> 3;
        lin = xcd * (nwg >> 3) + idx;
    }
    const int bm = (lin % nbm) * 128;
    const int bn = (lin / nbm) * 128;

    const int tid  = threadIdx.x;
    const int lane = tid & 63;
    const int w    = tid >> 6;
    const int wr   = w >> 1, wc = w & 1;

    f32x4 acc[4][4] = {};

    const int lrow = tid >> 2;
    const int lcol = (tid & 3) * 8;
    const bf16_t* ag = A + (size_t)(bm + lrow) * K + lcol;
    const bf16_t* bg = B + (size_t)(bn + lrow) * K + lcol;
    bf16_t* asl0 = As + lrow * 32 + lcol;
    bf16_t* asl1 = As + (lrow + 64) * 32 + lcol;
    bf16_t* bsl0 = Bs + lrow * 32 + lcol;
    bf16_t* bsl1 = Bs + (lrow + 64) * 32 + lcol;

    const int r16 = lane & 15;
    const int kh  = (lane >> 4) * 8;

    for (int k0 = 0; k0 < K; k0 += 32) {
        GLOAD_LDS16(ag + k0, asl0);
        GLOAD_LDS16(ag + (size_t)64 * K + k0, asl1);
        GLOAD_LDS16(bg + k0, bsl0);
        GLOAD_LDS16(bg + (size_t)64 * K + k0, bsl1);
        __syncthreads();

        bf16x8 af[4], bf[4];
#pragma unroll
        for (int mi = 0; mi < 4; ++mi)
            af[mi] = *(const bf16x8*)(As + (wr * 64 + mi * 16 + r16) * 32 + kh);
#pragma unroll
        for (int ni = 0; ni < 4; ++ni)
            bf[ni] = *(const bf16x8*)(Bs + (wc * 64 + ni * 16 + r16) * 32 + kh);
#pragma unroll
        for (int mi = 0; mi < 4; ++mi)
#pragma unroll
            for (int ni = 0; ni < 4; ++ni)
                acc[mi][ni] = MFMA(af[mi], bf[ni], acc[mi][ni]);
        __syncthreads();
    }

#pragma unroll
    for (int mi = 0; mi < 4; ++mi) {
        const int row0 = bm + wr * 64 + mi * 16 + (lane >> 4) * 4;
#pragma unroll
        for (int ni = 0; ni < 4; ++ni) {
            const int col = bn + wc * 64 + ni * 16 + r16;
            float bv = 0.f;
            if (BIAS) bv = bias[col];
#pragma unroll
            for (int r = 0; r < 4; ++r)
                C[(size_t)(row0 + r) * N + col] = acc[mi][ni][r] + bv;
        }
    }
}

// ---------------------------------------------------------------------------
// GEMM 256x256, BK=64, 8 waves (2M x 4N), 4-phase interleave with counted
// vmcnt (T2+T3+T4+T5 port). C[M,N] = A[M,K]*B[N,K]^T (+bias), bf16 in f32 out.
// LDS: 2 buffers x (A 256x64 + B 256x64) bf16 = 128 KB, XOR-swizzled:
//   16B-slot s of row r holds logical slot s^(r&7)  (involution; staged via
//   inverse-swizzled global source, read via swizzled ds_read — rule #21).
// Per K-tile: 4 phases, each = {ds_read subtile; stage 0-4 loads into regions
// freed by earlier phases; barrier; lgkmcnt(0); setprio(1); 16 MFMA;
// setprio(0); barrier}. 8 loads/tile; vmcnt(8) once per tile (phase 3).
// Requires M%256==0, N%256==0, K%64==0, K>=128.
// ---------------------------------------------------------------------------
template <int BIAS>
__global__ __launch_bounds__(512, 1) void gemm256_bf16_kernel(
    const bf16_t* __restrict__ A, const bf16_t* __restrict__ B,
    const float* __restrict__ bias, float* __restrict__ C,
    int M, int N, int K) {
    __shared__ __align__(16) bf16_t lds[2 * 2 * 16384];   // 128 KB

    const int NT = K >> 6;
    const int nbm = gridDim.y, nbn = gridDim.x;
    const int nwg = nbm * nbn;
    int lin = blockIdx.y * nbn + blockIdx.x;
    {   // bijective XCD swizzle (m204 q/r form)
        int q = nwg >> 3, r = nwg & 7, x = lin & 7, i = lin >> 3;
        lin = (x < r ? x * (q + 1) : r * (q + 1) + (x - r) * q) + i;
    }
    const int bm = (lin % nbm) * 256;   // bm fastest: B panel L2-resident
    const int bn = (lin / nbm) * 256;

    const int tid = threadIdx.x, lane = tid & 63;
    const int w = tid >> 6, wm = w >> 2, wn = w & 3;
    const int r16 = lane & 15, sl = lane >> 4, r7 = r16 & 7;

    // staging: thread covers 16B slot (tid&7) of row (tid>>3) per 64-row load;
    // inverse-swizzled source slot
    const int srow  = tid >> 3;
    const int sslot = (tid & 7) ^ (srow & 7);
    const bf16_t* agS = A + (size_t)(bm + srow) * K + sslot * 8;
    const bf16_t* bgS = B + (size_t)(bn + srow) * K + sslot * 8;

    // swizzled read column offsets (elements) for kstep 0/1
    const int colk0 = ((0 + sl) ^ r7) * 8;
    const int colk1 = ((4 + sl) ^ r7) * 8;
    const int arow = (wm * 128 + r16) * 64;
    const int brow = (wn * 64 + r16) * 64;

    f32x4 acc[8][4] = {};
    bf16x8 af[4][2], bf[4][2];

    // ---- prologue: stage tile 0 -> buf0, tile 1 -> buf1 ----
#pragma unroll
    for (int l = 0; l < 4; ++l)
        GLOAD_LDS16(agS + (size_t)(l * 64) * K, lds + l * 4096 + tid * 8);
#pragma unroll
    for (int l = 0; l < 4; ++l)
        GLOAD_LDS16(bgS + (size_t)(l * 64) * K, lds + 16384 + l * 4096 + tid * 8);
#pragma unroll
    for (int l = 0; l < 4; ++l)
        GLOAD_LDS16(agS + (size_t)(l * 64) * K + 64,
                    lds + 32768 + l * 4096 + tid * 8);
#pragma unroll
    for (int l = 0; l < 4; ++l)
        GLOAD_LDS16(bgS + (size_t)(l * 64) * K + 64,
                    lds + 49152 + l * 4096 + tid * 8);
    asm volatile("s_waitcnt vmcnt(8)" ::: "memory");   // tile 0 landed
    __builtin_amdgcn_sched_barrier(0);
    __builtin_amdgcn_s_barrier();

#pragma unroll 1
    for (int kt = 0; kt < NT; ++kt) {
        const int cur = kt & 1;
        const bf16_t* Ab = lds + cur * 32768;
        const bf16_t* Bb = Ab + 16384;
        bf16_t* Sb = lds + cur * 32768;          // stage dest = consumed buf
        const bool st = (kt + 2 < NT);
        const size_t kof = (size_t)(kt + 2) * 64;

        // ---------------- phase 0: fr0-3 x nf0-1 ----------------
#pragma unroll
        for (int fr = 0; fr < 4; ++fr) {
            af[fr][0] = *(const bf16x8*)(Ab + arow + fr * 1024 + colk0);
            af[fr][1] = *(const bf16x8*)(Ab + arow + fr * 1024 + colk1);
        }
#pragma unroll
        for (int nf = 0; nf < 2; ++nf) {
            bf[nf][0] = *(const bf16x8*)(Bb + brow + nf * 1024 + colk0);
            bf[nf][1] = *(const bf16x8*)(Bb + brow + nf * 1024 + colk1);
        }
        __builtin_amdgcn_sched_barrier(0);
        __builtin_amdgcn_s_barrier();
        asm volatile("s_waitcnt lgkmcnt(0)" ::: "memory");
        __builtin_amdgcn_sched_barrier(0);
        __builtin_amdgcn_s_setprio(1);
#pragma unroll
        for (int fr = 0; fr < 4; ++fr)
#pragma unroll
            for (int nf = 0; nf < 2; ++nf) {
                acc[fr][nf] = MFMA(af[fr][0], bf[nf][0], acc[fr][nf]);
                acc[fr][nf] = MFMA(af[fr][1], bf[nf][1], acc[fr][nf]);
            }
        __builtin_amdgcn_s_setprio(0);
        __builtin_amdgcn_sched_barrier(0);
        __builtin_amdgcn_s_barrier();

        // ---------------- phase 1: fr0-3 x nf2-3 ----------------
        // A rows 0-63 & 128-191 (loads 0,2) fully read in ph0 -> stage them.
#pragma unroll
        for (int nf = 2; nf < 4; ++nf) {
            bf[nf][0] = *(const bf16x8*)(Bb + brow + nf * 1024 + colk0);
            bf[nf][1] = *(const bf16x8*)(Bb + brow + nf * 1024 + colk1);
        }
        __builtin_amdgcn_sched_barrier(0);
        if (st) {
            GLOAD_LDS16(agS + kof, Sb + tid * 8);
            GLOAD_LDS16(agS + (size_t)128 * K + kof, Sb + 8192 + tid * 8);
        }
        __builtin_amdgcn_s_barrier();
        asm volatile("s_waitcnt lgkmcnt(0)" ::: "memory");
        __builtin_amdgcn_sched_barrier(0);
        __builtin_amdgcn_s_setprio(1);
#pragma unroll
        for (int fr = 0; fr < 4; ++fr)
#pragma unroll
            for (int nf = 2; nf < 4; ++nf) {
                acc[fr][nf] = MFMA(af[fr][0], bf[nf][0], acc[fr][nf]);
                acc[fr][nf] = MFMA(af[fr][1], bf[nf][1], acc[fr][nf]);
            }
        __builtin_amdgcn_s_setprio(0);
        __builtin_amdgcn_sched_barrier(0);
        __builtin_amdgcn_s_barrier();

        // ---------------- phase 2: fr4-7 x nf0-1 ----------------
        // B fully read in ph0+ph1 -> stage all 4 B loads.
#pragma unroll
        for (int fr = 0; fr < 4; ++fr) {
            af[fr][0] = *(const bf16x8*)(Ab + arow + (fr + 4) * 1024 + colk0);
            af[fr][1] = *(const bf16x8*)(Ab + arow + (fr + 4) * 1024 + colk1);
        }
        __builtin_amdgcn_sched_barrier(0);
        if (st) {
#pragma unroll
            for (int l = 0; l < 4; ++l)
                GLOAD_LDS16(bgS + (size_t)(l * 64) * K + kof,
                            Sb + 16384 + l * 4096 + tid * 8);
        }
        __builtin_amdgcn_s_barrier();
        asm volatile("s_waitcnt lgkmcnt(0)" ::: "memory");
        __builtin_amdgcn_sched_barrier(0);
        __builtin_amdgcn_s_setprio(1);
#pragma unroll
        for (int fr = 0; fr < 4; ++fr)
#pragma unroll
            for (int nf = 0; nf < 2; ++nf) {
                acc[fr + 4][nf] = MFMA(af[fr][0], bf[nf][0], acc[fr + 4][nf]);
                acc[fr + 4][nf] = MFMA(af[fr][1], bf[nf][1], acc[fr + 4][nf]);
            }
        __builtin_amdgcn_s_setprio(0);
        __builtin_amdgcn_sched_barrier(0);
        __builtin_amdgcn_s_barrier();

        // ---------------- phase 3: fr4-7 x nf2-3 ----------------
        // A rows 64-127 & 192-255 (loads 1,3) fully read in ph2 -> stage.
        if (st) {
            GLOAD_LDS16(agS + (size_t)64 * K + kof, Sb + 4096 + tid * 8);
            GLOAD_LDS16(agS + (size_t)192 * K + kof, Sb + 12288 + tid * 8);
        }
        if (kt + 2 < NT) {
            asm volatile("s_waitcnt vmcnt(8)" ::: "memory");  // next tile landed
        } else if (kt + 1 < NT) {
            asm volatile("s_waitcnt vmcnt(0)" ::: "memory");
        }
        __builtin_amdgcn_sched_barrier(0);
        __builtin_amdgcn_s_setprio(1);
#pragma unroll
        for (int fr = 0; fr < 4; ++fr)
#pragma unroll
            for (int nf = 2; nf < 4; ++nf) {
                acc[fr + 4][nf] = MFMA(af[fr][0], bf[nf][0], acc[fr + 4][nf]);
                acc[fr + 4][nf] = MFMA(af[fr][1], bf[nf][1], acc[fr + 4][nf]);
            }
        __builtin_amdgcn_s_setprio(0);
        __builtin_amdgcn_sched_barrier(0);
        __builtin_amdgcn_s_barrier();
    }

    // ---- epilogue ----
#pragma unroll
    for (int fr = 0; fr < 8; ++fr) {
        const int row0 = bm + wm * 128 + fr * 16 + sl * 4;
#pragma unroll
        for (int nf = 0; nf < 4; ++nf) {
            const int col = bn + wn * 64 + nf * 16 + r16;
            float bv = 0.f;
            if (BIAS) bv = bias[col];
#pragma unroll
            for (int r = 0; r < 4; ++r)
                C[(size_t)(row0 + r) * N + col] = acc[fr][nf][r] + bv;
        }
    }
}

// ---------------------------------------------------------------------------
// Persistent GRU layer kernel, v3 (unchanged from R5).
// ---------------------------------------------------------------------------
union U64cast { bf16x4 v; unsigned long long u; };

__global__ __launch_bounds__(256, 1) void gru_layer_kernel(
    const bf16_t* __restrict__ h0b, const float* __restrict__ h0f,
    const bf16_t* __restrict__ whh, const float* __restrict__ bhh,
    const float* __restrict__ Gi, bf16_t* __restrict__ Hb,
    unsigned* __restrict__ flags) {
    __shared__ __align__(16) float Sg[4][3][128][16];   // 96 KB

    const int tid  = threadIdx.x;
    const int lane = tid & 63;
    const int w    = tid >> 6;          // k-slice owner
    const int bid  = blockIdx.x;
    const int c0   = bid * 16;
    const int r16  = lane & 15;
    const int kq   = (lane >> 4) * 8;   // k sub-offset within 32-frag

    bf16x8 wf[3][8];
#pragma unroll
    for (int g = 0; g < 3; ++g)
#pragma unroll
        for (int kf = 0; kf < 8; ++kf)
            wf[g][kf] = *(const bf16x8*)(
                whh + (size_t)(g * HID + c0 + r16) * HID + w * 256 + kf * 32 + kq);

    const int cg   = tid & 3;
    const int rloc = tid >> 2;
    const int ce   = c0 + cg * 4;

    float bh[3][4];
#pragma unroll
    for (int g = 0; g < 3; ++g)
#pragma unroll
        for (int j = 0; j < 4; ++j) bh[g][j] = bhh[g * HID + ce + j];

    float hp[2][4];
    f32x4 gi[2][3];
#pragma unroll
    for (int i = 0; i < 2; ++i) {
        const int row = rloc + i * 64;
#pragma unroll
        for (int j = 0; j < 4; ++j)
            hp[i][j] = h0f[(size_t)row * HID + ce + j];
        const size_t gb = (size_t)row * G3 + ce;   // t = 0
        gi[i][0] = *(const f32x4*)(Gi + gb);
        gi[i][1] = *(const f32x4*)(Gi + gb + HID);
        gi[i][2] = *(const f32x4*)(Gi + gb + 2 * HID);
    }

    for (int t = 0; t < T_SEQ; ++t) {
        const bf16_t* hb = t ? Hb + (size_t)(t - 1) * BHID : h0b;

        f32x4 acc[3][8] = {};
        bf16x8 af[4][8];
#define LD_GROUP(buf, kf)                                                    \
    {                                                                        \
        const int kbase = w * 256 + (kf) * 32 + kq;                          \
        _Pragma("unroll") for (int rf = 0; rf < 8; ++rf)                     \
            af[buf][rf] =                                                    \
                *(const bf16x8*)(hb + (size_t)(rf * 16 + r16) * HID + kbase); \
    }
        LD_GROUP(0, 0)
        LD_GROUP(1, 1)
        LD_GROUP(2, 2)
#pragma unroll
        for (int kf = 0; kf < 8; ++kf) {
            if (kf + 3 < 8) LD_GROUP((kf + 3) & 3, kf + 3)
#pragma unroll
            for (int rf = 0; rf < 8; ++rf) {
                acc[0][rf] = MFMA(af[kf & 3][rf], wf[0][kf], acc[0][rf]);
                acc[1][rf] = MFMA(af[kf & 3][rf], wf[1][kf], acc[1][rf]);
                acc[2][rf] = MFMA(af[kf & 3][rf], wf[2][kf], acc[2][rf]);
            }
        }
#undef LD_GROUP

#pragma unroll
        for (int g = 0; g < 3; ++g)
#pragma unroll
            for (int rf = 0; rf < 8; ++rf)
#pragma unroll
                for (int r = 0; r < 4; ++r)
                    Sg[w][g][rf * 16 + (lane >> 4) * 4 + r][r16] = acc[g][rf][r];
        __syncthreads();

#pragma unroll
        for (int i = 0; i < 2; ++i) {
            const int row = rloc + i * 64;
            f32x4 gr = *(const f32x4*)&Sg[0][0][row][cg * 4];
            f32x4 gz = *(const f32x4*)&Sg[0][1][row][cg * 4];
            f32x4 gn = *(const f32x4*)&Sg[0][2][row][cg * 4];
#pragma unroll
            for (int ks = 1; ks < 4; ++ks) {
                gr += *(const f32x4*)&Sg[ks][0][row][cg * 4];
                gz += *(const f32x4*)&Sg[ks][1][row][cg * 4];
                gn += *(const f32x4*)&Sg[ks][2][row][cg * 4];
            }
            U64cast hb4;
#pragma unroll
            for (int j = 0; j < 4; ++j) {
                float rr = 1.f / (1.f + __expf(-(gi[i][0][j] + gr[j] + bh[0][j])));
                float zz = 1.f / (1.f + __expf(-(gi[i][1][j] + gz[j] + bh[1][j])));
                float nn = tanhf(gi[i][2][j] + rr * (gn[j] + bh[2][j]));
                float h  = (1.f - zz) * nn + zz * hp[i][j];
                hp[i][j] = h;
                hb4.v[j] = (bf16_t)h;
            }
            __hip_atomic_store(
                (unsigned long long*)(Hb + (size_t)t * BHID +
                                      (size_t)row * HID + ce),
                hb4.u, __ATOMIC_RELAXED, __HIP_MEMORY_SCOPE_SYSTEM);
        }

        if (t < T_SEQ - 1) {
            __syncthreads();
            if (tid == 0)
                __hip_atomic_store(&flags[bid], (unsigned)(t + 1),
                                   __ATOMIC_RELAXED, __HIP_MEMORY_SCOPE_SYSTEM);
#pragma unroll
            for (int i = 0; i < 2; ++i) {
                const size_t gb =
                    ((size_t)(t + 1) * BATCH + rloc + i * 64) * G3 + ce;
                gi[i][0] = *(const f32x4*)(Gi + gb);
                gi[i][1] = *(const f32x4*)(Gi + gb + HID);
                gi[i][2] = *(const f32x4*)(Gi + gb + 2 * HID);
            }
            if (tid < 64) {
                while (__hip_atomic_load(&flags[tid], __ATOMIC_RELAXED,
                                         __HIP_MEMORY_SCOPE_SYSTEM) <
                       (unsigned)(t + 1))
                    __builtin_amdgcn_s_sleep(1);
            }
            __syncthreads();
        }
    }
}

// ---------------------------------------------------------------------------
extern "C" void kernel_launch(void* const* d_in, const int* in_sizes, int n_in,
                              void* d_out, int out_size, void* d_ws, size_t ws_size,
                              hipStream_t stream) {
    const int*   x        = (const int*)d_in[0];
    const float* enc_hid  = (const float*)d_in[2];   // [2,128,1024]
    const float* emb      = (const float*)d_in[3];
    const float* w_ih0    = (const float*)d_in[4];
    const float* w_hh0    = (const float*)d_in[5];
    const float* b_ih0    = (const float*)d_in[6];
    const float* b_hh0    = (const float*)d_in[7];
    const float* w_ih1    = (const float*)d_in[8];
    const float* w_hh1    = (const float*)d_in[9];
    const float* b_ih1    = (const float*)d_in[10];
    const float* b_hh1    = (const float*)d_in[11];
    const float* w_dec    = (const float*)d_in[12];
    const float* b_dec    = (const float*)d_in[13];
    float* out = (float*)d_out;

    char* ws = (char*)d_ws;
    size_t off = 0;
    auto alloc = [&](size_t bytes) {
        void* p = ws + off;
        off += (bytes + 255) & ~(size_t)255;
        return p;
    };
    unsigned* flags0 = (unsigned*)alloc(NBLK * 4);   // packed 4B flags
    unsigned* flags1 = (unsigned*)alloc(NBLK * 4);
    bf16_t* Xb     = (bf16_t*)alloc((size_t)MROWS * EMB * 2);
    bf16_t* Wih0b  = (bf16_t*)alloc((size_t)G3 * EMB * 2);
    bf16_t* Whh0b  = (bf16_t*)alloc((size_t)G3 * HID * 2);
    bf16_t* Wih1b  = (bf16_t*)alloc((size_t)G3 * HID * 2);
    bf16_t* Whh1b  = (bf16_t*)alloc((size_t)G3 * HID * 2);
    bf16_t* Wdecb  = (bf16_t*)alloc((size_t)VOC * HID * 2);
    bf16_t* h0ib   = (bf16_t*)alloc((size_t)BATCH * HID * 2);
    bf16_t* h1ib   = (bf16_t*)alloc((size_t)BATCH * HID * 2);
    float*  Gi     = (float*)alloc((size_t)MROWS * G3 * 4);
    bf16_t* H0b    = (bf16_t*)alloc((size_t)MROWS * HID * 2);
    bf16_t* H1b    = (bf16_t*)alloc((size_t)MROWS * HID * 2);

    hipMemsetAsync(flags0, 0, 512, stream);   // covers flags0 + flags1

    auto cvt = [&](const float* src, bf16_t* dst, int n) {
        int blocks = (n + 1023) / 1024;
        f32_to_bf16_kernel<<<blocks, 256, 0, stream>>>(src, dst, n);
    };

    cvt(w_ih0, Wih0b, G3 * EMB);
    cvt(w_hh0, Whh0b, G3 * HID);
    cvt(w_ih1, Wih1b, G3 * HID);
    cvt(w_hh1, Whh1b, G3 * HID);
    cvt(w_dec, Wdecb, VOC * HID);
    cvt(enc_hid, h0ib, BATCH * HID);
    cvt(enc_hid + BATCH * HID, h1ib, BATCH * HID);

    embed_kernel<<<MROWS, 128, 0, stream>>>(x, emb, Xb);

    // Gi0 = X @ w_ih0^T + b_ih0  -> [4096, 3072]
    gemm_bf16_kernel<1><<<dim3(G3 / 128, MROWS / 128), 256, 0, stream>>>(
        Xb, Wih0b, b_ih0, Gi, MROWS, G3, EMB);

    // layer 0: persistent scan
    gru_layer_kernel<<<NBLK, 256, 0, stream>>>(
        h0ib, enc_hid, Whh0b, b_hh0, Gi, H0b, flags0);

    // Gi1 = H0 @ w_ih1^T + b_ih1 -> [4096, 3072]
    gemm_bf16_kernel<1><<<dim3(G3 / 128, MROWS / 128), 256, 0, stream>>>(
        H0b, Wih1b, b_ih1, Gi, MROWS, G3, HID);

    // layer 1: persistent scan
    gru_layer_kernel<<<NBLK, 256, 0, stream>>>(
        h1ib, enc_hid + BATCH * HID, Whh1b, b_hh1, Gi, H1b, flags1);

    // logits = H1 @ w_dec^T + b_dec -> [4096, 32000]  (256² 8-phase port)
    gemm256_bf16_kernel<1><<<dim3(VOC / 256, MROWS / 256), 512, 0, stream>>>(
        H1b, Wdecb, b_dec, out, MROWS, VOC, HID);
}

// Round 7
// 947.010 us; speedup vs baseline: 2.3013x; 1.3208x over previous
//
#include <hip/hip_runtime.h>
#include <hip/hip_bf16.h>
#include <stdint.h>

#define T_SEQ 32
#define BATCH 128
#define EMB   512
#define HID   1024
#define VOC   32000
#define G3    (3 * HID)            // 3072
#define MROWS (T_SEQ * BATCH)      // 4096
#define BHID  (BATCH * HID)

typedef __bf16 bf16_t;
typedef __bf16 bf16x8 __attribute__((ext_vector_type(8)));
typedef __bf16 bf16x4 __attribute__((ext_vector_type(4)));
typedef float  f32x4  __attribute__((ext_vector_type(4)));

#define MFMA(a, b, c) __builtin_amdgcn_mfma_f32_16x16x32_bf16((a), (b), (c), 0, 0, 0)

// ---------------------------------------------------------------------------
// f32 -> bf16 conversion (vectorized)
// ---------------------------------------------------------------------------
__global__ void f32_to_bf16_kernel(const float* __restrict__ in,
                                   bf16_t* __restrict__ out, int n) {
    int i = (blockIdx.x * blockDim.x + threadIdx.x) * 4;
    if (i + 3 < n) {
        float4 v = *(const float4*)(in + i);
        out[i + 0] = (bf16_t)v.x;
        out[i + 1] = (bf16_t)v.y;
        out[i + 2] = (bf16_t)v.z;
        out[i + 3] = (bf16_t)v.w;
    } else {
        for (; i < n; ++i) out[i] = (bf16_t)in[i];
    }
}

// ---------------------------------------------------------------------------
// Embedding gather
// ---------------------------------------------------------------------------
__global__ void embed_kernel(const int* __restrict__ x,
                             const float* __restrict__ emb,
                             bf16_t* __restrict__ X) {
    int m = blockIdx.x;            // 0..4095
    int t = m >> 7, b = m & 127;
    int tok = (t == 0) ? 1 : x[b * T_SEQ + t];
    const float* src = emb + (size_t)tok * EMB;
    bf16_t* dst = X + (size_t)m * EMB;
    int c = threadIdx.x * 4;
    float4 v = *(const float4*)(src + c);
    dst[c + 0] = (bf16_t)v.x;
    dst[c + 1] = (bf16_t)v.y;
    dst[c + 2] = (bf16_t)v.z;
    dst[c + 3] = (bf16_t)v.w;
}

// ---------------------------------------------------------------------------
#define GLOAD_LDS16(g, l)                                                    \
    __builtin_amdgcn_global_load_lds(                                        \
        (const __attribute__((address_space(1))) void*)(g),                  \
        (__attribute__((address_space(3))) void*)(l), 16, 0, 0)

// ---------------------------------------------------------------------------
// GEMM 128x128 (m97 structure) — used for the Gi0 GEMM.
// ---------------------------------------------------------------------------
template <int BIAS>
__global__ __launch_bounds__(256) void gemm_bf16_kernel(
    const bf16_t* __restrict__ A, const bf16_t* __restrict__ B,
    const float* __restrict__ bias, float* __restrict__ C,
    int M, int N, int K) {
    __shared__ __align__(16) bf16_t As[128 * 32];
    __shared__ __align__(16) bf16_t Bs[128 * 32];

    const int nbm = gridDim.y, nbn = gridDim.x;
    const int nwg = nbm * nbn;
    int lin = blockIdx.y * nbn + blockIdx.x;
    if ((nwg & 7) == 0) {
        int xcd = lin & 7, idx = lin >> 3;
        lin = xcd * (nwg >> 3) + idx;
    }
    const int bm = (lin % nbm) * 128;
    const int bn = (lin / nbm) * 128;

    const int tid  = threadIdx.x;
    const int lane = tid & 63;
    const int w    = tid >> 6;
    const int wr   = w >> 1, wc = w & 1;

    f32x4 acc[4][4] = {};

    const int lrow = tid >> 2;
    const int lcol = (tid & 3) * 8;
    const bf16_t* ag = A + (size_t)(bm + lrow) * K + lcol;
    const bf16_t* bg = B + (size_t)(bn + lrow) * K + lcol;
    bf16_t* asl0 = As + lrow * 32 + lcol;
    bf16_t* asl1 = As + (lrow + 64) * 32 + lcol;
    bf16_t* bsl0 = Bs + lrow * 32 + lcol;
    bf16_t* bsl1 = Bs + (lrow + 64) * 32 + lcol;

    const int r16 = lane & 15;
    const int kh  = (lane >> 4) * 8;

    for (int k0 = 0; k0 < K; k0 += 32) {
        GLOAD_LDS16(ag + k0, asl0);
        GLOAD_LDS16(ag + (size_t)64 * K + k0, asl1);
        GLOAD_LDS16(bg + k0, bsl0);
        GLOAD_LDS16(bg + (size_t)64 * K + k0, bsl1);
        __syncthreads();

        bf16x8 af[4], bf[4];
#pragma unroll
        for (int mi = 0; mi < 4; ++mi)
            af[mi] = *(const bf16x8*)(As + (wr * 64 + mi * 16 + r16) * 32 + kh);
#pragma unroll
        for (int ni = 0; ni < 4; ++ni)
            bf[ni] = *(const bf16x8*)(Bs + (wc * 64 + ni * 16 + r16) * 32 + kh);
#pragma unroll
        for (int mi = 0; mi < 4; ++mi)
#pragma unroll
            for (int ni = 0; ni < 4; ++ni)
                acc[mi][ni] = MFMA(af[mi], bf[ni], acc[mi][ni]);
        __syncthreads();
    }

#pragma unroll
    for (int mi = 0; mi < 4; ++mi) {
        const int row0 = bm + wr * 64 + mi * 16 + (lane >> 4) * 4;
#pragma unroll
        for (int ni = 0; ni < 4; ++ni) {
            const int col = bn + wc * 64 + ni * 16 + r16;
            float bv = 0.f;
            if (BIAS) bv = bias[col];
#pragma unroll
            for (int r = 0; r < 4; ++r)
                C[(size_t)(row0 + r) * N + col] = acc[mi][ni][r] + bv;
        }
    }
}

// ---------------------------------------------------------------------------
// GEMM 256x256, BK=64, 8 waves, 4-phase interleave, counted vmcnt, LDS XOR
// swizzle (unchanged from R6 — verified).
// ---------------------------------------------------------------------------
template <int BIAS>
__global__ __launch_bounds__(512, 1) void gemm256_bf16_kernel(
    const bf16_t* __restrict__ A, const bf16_t* __restrict__ B,
    const float* __restrict__ bias, float* __restrict__ C,
    int M, int N, int K) {
    __shared__ __align__(16) bf16_t lds[2 * 2 * 16384];   // 128 KB

    const int NT = K >> 6;
    const int nbm = gridDim.y, nbn = gridDim.x;
    const int nwg = nbm * nbn;
    int lin = blockIdx.y * nbn + blockIdx.x;
    {
        int q = nwg >> 3, r = nwg & 7, x = lin & 7, i = lin >> 3;
        lin = (x < r ? x * (q + 1) : r * (q + 1) + (x - r) * q) + i;
    }
    const int bm = (lin % nbm) * 256;
    const int bn = (lin / nbm) * 256;

    const int tid = threadIdx.x, lane = tid & 63;
    const int w = tid >> 6, wm = w >> 2, wn = w & 3;
    const int r16 = lane & 15, sl = lane >> 4, r7 = r16 & 7;

    const int srow  = tid >> 3;
    const int sslot = (tid & 7) ^ (srow & 7);
    const bf16_t* agS = A + (size_t)(bm + srow) * K + sslot * 8;
    const bf16_t* bgS = B + (size_t)(bn + srow) * K + sslot * 8;

    const int colk0 = ((0 + sl) ^ r7) * 8;
    const int colk1 = ((4 + sl) ^ r7) * 8;
    const int arow = (wm * 128 + r16) * 64;
    const int brow = (wn * 64 + r16) * 64;

    f32x4 acc[8][4] = {};
    bf16x8 af[4][2], bf[4][2];

#pragma unroll
    for (int l = 0; l < 4; ++l)
        GLOAD_LDS16(agS + (size_t)(l * 64) * K, lds + l * 4096 + tid * 8);
#pragma unroll
    for (int l = 0; l < 4; ++l)
        GLOAD_LDS16(bgS + (size_t)(l * 64) * K, lds + 16384 + l * 4096 + tid * 8);
#pragma unroll
    for (int l = 0; l < 4; ++l)
        GLOAD_LDS16(agS + (size_t)(l * 64) * K + 64,
                    lds + 32768 + l * 4096 + tid * 8);
#pragma unroll
    for (int l = 0; l < 4; ++l)
        GLOAD_LDS16(bgS + (size_t)(l * 64) * K + 64,
                    lds + 49152 + l * 4096 + tid * 8);
    asm volatile("s_waitcnt vmcnt(8)" ::: "memory");
    __builtin_amdgcn_sched_barrier(0);
    __builtin_amdgcn_s_barrier();

#pragma unroll 1
    for (int kt = 0; kt < NT; ++kt) {
        const int cur = kt & 1;
        const bf16_t* Ab = lds + cur * 32768;
        const bf16_t* Bb = Ab + 16384;
        bf16_t* Sb = lds + cur * 32768;
        const bool st = (kt + 2 < NT);
        const size_t kof = (size_t)(kt + 2) * 64;

        // phase 0
#pragma unroll
        for (int fr = 0; fr < 4; ++fr) {
            af[fr][0] = *(const bf16x8*)(Ab + arow + fr * 1024 + colk0);
            af[fr][1] = *(const bf16x8*)(Ab + arow + fr * 1024 + colk1);
        }
#pragma unroll
        for (int nf = 0; nf < 2; ++nf) {
            bf[nf][0] = *(const bf16x8*)(Bb + brow + nf * 1024 + colk0);
            bf[nf][1] = *(const bf16x8*)(Bb + brow + nf * 1024 + colk1);
        }
        __builtin_amdgcn_sched_barrier(0);
        __builtin_amdgcn_s_barrier();
        asm volatile("s_waitcnt lgkmcnt(0)" ::: "memory");
        __builtin_amdgcn_sched_barrier(0);
        __builtin_amdgcn_s_setprio(1);
#pragma unroll
        for (int fr = 0; fr < 4; ++fr)
#pragma unroll
            for (int nf = 0; nf < 2; ++nf) {
                acc[fr][nf] = MFMA(af[fr][0], bf[nf][0], acc[fr][nf]);
                acc[fr][nf] = MFMA(af[fr][1], bf[nf][1], acc[fr][nf]);
            }
        __builtin_amdgcn_s_setprio(0);
        __builtin_amdgcn_sched_barrier(0);
        __builtin_amdgcn_s_barrier();

        // phase 1
#pragma unroll
        for (int nf = 2; nf < 4; ++nf) {
            bf[nf][0] = *(const bf16x8*)(Bb + brow + nf * 1024 + colk0);
            bf[nf][1] = *(const bf16x8*)(Bb + brow + nf * 1024 + colk1);
        }
        __builtin_amdgcn_sched_barrier(0);
        if (st) {
            GLOAD_LDS16(agS + kof, Sb + tid * 8);
            GLOAD_LDS16(agS + (size_t)128 * K + kof, Sb + 8192 + tid * 8);
        }
        __builtin_amdgcn_s_barrier();
        asm volatile("s_waitcnt lgkmcnt(0)" ::: "memory");
        __builtin_amdgcn_sched_barrier(0);
        __builtin_amdgcn_s_setprio(1);
#pragma unroll
        for (int fr = 0; fr < 4; ++fr)
#pragma unroll
            for (int nf = 2; nf < 4; ++nf) {
                acc[fr][nf] = MFMA(af[fr][0], bf[nf][0], acc[fr][nf]);
                acc[fr][nf] = MFMA(af[fr][1], bf[nf][1], acc[fr][nf]);
            }
        __builtin_amdgcn_s_setprio(0);
        __builtin_amdgcn_sched_barrier(0);
        __builtin_amdgcn_s_barrier();

        // phase 2
#pragma unroll
        for (int fr = 0; fr < 4; ++fr) {
            af[fr][0] = *(const bf16x8*)(Ab + arow + (fr + 4) * 1024 + colk0);
            af[fr][1] = *(const bf16x8*)(Ab + arow + (fr + 4) * 1024 + colk1);
        }
        __builtin_amdgcn_sched_barrier(0);
        if (st) {
#pragma unroll
            for (int l = 0; l < 4; ++l)
                GLOAD_LDS16(bgS + (size_t)(l * 64) * K + kof,
                            Sb + 16384 + l * 4096 + tid * 8);
        }
        __builtin_amdgcn_s_barrier();
        asm volatile("s_waitcnt lgkmcnt(0)" ::: "memory");
        __builtin_amdgcn_sched_barrier(0);
        __builtin_amdgcn_s_setprio(1);
#pragma unroll
        for (int fr = 0; fr < 4; ++fr)
#pragma unroll
            for (int nf = 0; nf < 2; ++nf) {
                acc[fr + 4][nf] = MFMA(af[fr][0], bf[nf][0], acc[fr + 4][nf]);
                acc[fr + 4][nf] = MFMA(af[fr][1], bf[nf][1], acc[fr + 4][nf]);
            }
        __builtin_amdgcn_s_setprio(0);
        __builtin_amdgcn_sched_barrier(0);
        __builtin_amdgcn_s_barrier();

        // phase 3
        if (st) {
            GLOAD_LDS16(agS + (size_t)64 * K + kof, Sb + 4096 + tid * 8);
            GLOAD_LDS16(agS + (size_t)192 * K + kof, Sb + 12288 + tid * 8);
        }
        if (kt + 2 < NT) {
            asm volatile("s_waitcnt vmcnt(8)" ::: "memory");
        } else if (kt + 1 < NT) {
            asm volatile("s_waitcnt vmcnt(0)" ::: "memory");
        }
        __builtin_amdgcn_sched_barrier(0);
        __builtin_amdgcn_s_setprio(1);
#pragma unroll
        for (int fr = 0; fr < 4; ++fr)
#pragma unroll
            for (int nf = 2; nf < 4; ++nf) {
                acc[fr + 4][nf] = MFMA(af[fr][0], bf[nf][0], acc[fr + 4][nf]);
                acc[fr + 4][nf] = MFMA(af[fr][1], bf[nf][1], acc[fr + 4][nf]);
            }
        __builtin_amdgcn_s_setprio(0);
        __builtin_amdgcn_sched_barrier(0);
        __builtin_amdgcn_s_barrier();
    }

#pragma unroll
    for (int fr = 0; fr < 8; ++fr) {
        const int row0 = bm + wm * 128 + fr * 16 + sl * 4;
#pragma unroll
        for (int nf = 0; nf < 4; ++nf) {
            const int col = bn + wn * 64 + nf * 16 + r16;
            float bv = 0.f;
            if (BIAS) bv = bias[col];
#pragma unroll
            for (int r = 0; r < 4; ++r)
                C[(size_t)(row0 + r) * N + col] = acc[fr][nf][r] + bv;
        }
    }
}

// ---------------------------------------------------------------------------
// Fused dataflow scan: 192 blocks, three roles of 64 (16 H-cols each):
//  role 0 (L0): h0(t) = GRU(h0(t-1), Gi0[t])          -> H0b[t] (sc)
//  role 1 (G):  gi1(t) = h0(t) @ w_ih1^T + b_ih1       -> Gi slot t (sc, f32)
//  role 2 (L1): h1(t) = GRU(h1(t-1), gi1(t) sc-read)   -> H1b[t] (sc)
// Stages run staggered-concurrent; each polls only its producer flags.
// Gi slot reuse is safe: G writes slot t only after L0flag>=t+1 (L0's single
// read of slot t precedes its flag t+1). L1 reads gi with SYSTEM-scope loads
// (plain loads could hit stale Gi0 lines in L2).
// ---------------------------------------------------------------------------
union U64cast  { bf16x4 v; unsigned long long u; };
union U128cast { f32x4 v; unsigned long long u[2]; };

__global__ __launch_bounds__(256, 1) void fused_scan_kernel(
    const bf16_t* __restrict__ h0ib, const bf16_t* __restrict__ h1ib,
    const float* __restrict__ enc_hid,
    const bf16_t* __restrict__ whh0, const bf16_t* __restrict__ wih1,
    const bf16_t* __restrict__ whh1,
    const float* __restrict__ bhh0, const float* __restrict__ bih1,
    const float* __restrict__ bhh1,
    float* __restrict__ Gi, bf16_t* __restrict__ H0b,
    bf16_t* __restrict__ H1b, unsigned* __restrict__ flags) {
    __shared__ __align__(16) float Sg[4][3][128][16];   // 96 KB

    const int tid  = threadIdx.x;
    const int lane = tid & 63;
    const int w    = tid >> 6;          // k-slice owner
    const int role = blockIdx.x >> 6;   // 0=L0, 1=G, 2=L1
    const int cb   = blockIdx.x & 63;
    const int c0   = cb * 16;
    const int r16  = lane & 15;
    const int kq   = (lane >> 4) * 8;

    const bf16_t* whh = role == 0 ? whh0 : (role == 1 ? wih1 : whh1);
    const float*  bia = role == 0 ? bhh0 : (role == 1 ? bih1 : bhh1);

    // stationary weights
    bf16x8 wf[3][8];
#pragma unroll
    for (int g = 0; g < 3; ++g)
#pragma unroll
        for (int kf = 0; kf < 8; ++kf)
            wf[g][kf] = *(const bf16x8*)(
                whh + (size_t)(g * HID + c0 + r16) * HID + w * 256 + kf * 32 + kq);

    const int cg   = tid & 3;
    const int rloc = tid >> 2;
    const int ce   = c0 + cg * 4;

    float bh[3][4];
#pragma unroll
    for (int g = 0; g < 3; ++g)
#pragma unroll
        for (int j = 0; j < 4; ++j) bh[g][j] = bia[g * HID + ce + j];

    float hp[2][4];
    if (role != 1) {
        const float* h0f = enc_hid + (role == 2 ? BHID : 0);
#pragma unroll
        for (int i = 0; i < 2; ++i)
#pragma unroll
            for (int j = 0; j < 4; ++j)
                hp[i][j] = h0f[(size_t)(rloc + i * 64) * HID + ce + j];
    }

    for (int t = 0; t < T_SEQ; ++t) {
        // ---- wait on producers ----
        if (role == 0) {
            if (t && tid < 64)
                while (__hip_atomic_load(&flags[tid], __ATOMIC_RELAXED,
                                         __HIP_MEMORY_SCOPE_SYSTEM) <
                       (unsigned)t)
                    __builtin_amdgcn_s_sleep(1);
        } else if (role == 1) {
            if (tid < 64)
                while (__hip_atomic_load(&flags[tid], __ATOMIC_RELAXED,
                                         __HIP_MEMORY_SCOPE_SYSTEM) <
                       (unsigned)(t + 1))
                    __builtin_amdgcn_s_sleep(1);
        } else {
            if (tid < 64) {
                while (__hip_atomic_load(&flags[64 + tid], __ATOMIC_RELAXED,
                                         __HIP_MEMORY_SCOPE_SYSTEM) <
                       (unsigned)(t + 1))
                    __builtin_amdgcn_s_sleep(1);
            } else if (tid < 128 && t) {
                while (__hip_atomic_load(&flags[128 + tid - 64],
                                         __ATOMIC_RELAXED,
                                         __HIP_MEMORY_SCOPE_SYSTEM) <
                       (unsigned)t)
                    __builtin_amdgcn_s_sleep(1);
            }
        }
        __syncthreads();

        // ---- gi load (roles 0, 2) ----
        f32x4 gi[2][3];
        if (role == 0) {
#pragma unroll
            for (int i = 0; i < 2; ++i) {
                const size_t gb =
                    ((size_t)t * BATCH + rloc + i * 64) * G3 + ce;
                gi[i][0] = *(const f32x4*)(Gi + gb);
                gi[i][1] = *(const f32x4*)(Gi + gb + HID);
                gi[i][2] = *(const f32x4*)(Gi + gb + 2 * HID);
            }
        } else if (role == 2) {
#pragma unroll
            for (int i = 0; i < 2; ++i) {
                const size_t gb =
                    ((size_t)t * BATCH + rloc + i * 64) * G3 + ce;
#pragma unroll
                for (int g = 0; g < 3; ++g) {
                    U128cast u;
                    const unsigned long long* p =
                        (const unsigned long long*)(Gi + gb + g * HID);
                    u.u[0] = __hip_atomic_load(p, __ATOMIC_RELAXED,
                                               __HIP_MEMORY_SCOPE_SYSTEM);
                    u.u[1] = __hip_atomic_load(p + 1, __ATOMIC_RELAXED,
                                               __HIP_MEMORY_SCOPE_SYSTEM);
                    gi[i][g] = u.v;
                }
            }
        }

        // ---- A source ----
        const bf16_t* hb =
            role == 0 ? (t ? H0b + (size_t)(t - 1) * BHID : h0ib)
          : role == 1 ? (H0b + (size_t)t * BHID)
                      : (t ? H1b + (size_t)(t - 1) * BHID : h1ib);

        // ---- MFMA phase: 4-deep pipelined af loads ----
        f32x4 acc[3][8] = {};
        bf16x8 af[4][8];
#define LD_GROUP(buf, kf)                                                    \
    {                                                                        \
        const int kbase = w * 256 + (kf) * 32 + kq;                          \
        _Pragma("unroll") for (int rf = 0; rf < 8; ++rf)                     \
            af[buf][rf] =                                                    \
                *(const bf16x8*)(hb + (size_t)(rf * 16 + r16) * HID + kbase); \
    }
        LD_GROUP(0, 0)
        LD_GROUP(1, 1)
        LD_GROUP(2, 2)
#pragma unroll
        for (int kf = 0; kf < 8; ++kf) {
            if (kf + 3 < 8) LD_GROUP((kf + 3) & 3, kf + 3)
#pragma unroll
            for (int rf = 0; rf < 8; ++rf) {
                acc[0][rf] = MFMA(af[kf & 3][rf], wf[0][kf], acc[0][rf]);
                acc[1][rf] = MFMA(af[kf & 3][rf], wf[1][kf], acc[1][rf]);
                acc[2][rf] = MFMA(af[kf & 3][rf], wf[2][kf], acc[2][rf]);
            }
        }
#undef LD_GROUP

#pragma unroll
        for (int g = 0; g < 3; ++g)
#pragma unroll
            for (int rf = 0; rf < 8; ++rf)
#pragma unroll
                for (int r = 0; r < 4; ++r)
                    Sg[w][g][rf * 16 + (lane >> 4) * 4 + r][r16] = acc[g][rf][r];
        __syncthreads();

        // ---- epilogue ----
#pragma unroll
        for (int i = 0; i < 2; ++i) {
            const int row = rloc + i * 64;
            f32x4 gr = *(const f32x4*)&Sg[0][0][row][cg * 4];
            f32x4 gz = *(const f32x4*)&Sg[0][1][row][cg * 4];
            f32x4 gn = *(const f32x4*)&Sg[0][2][row][cg * 4];
#pragma unroll
            for (int ks = 1; ks < 4; ++ks) {
                gr += *(const f32x4*)&Sg[ks][0][row][cg * 4];
                gz += *(const f32x4*)&Sg[ks][1][row][cg * 4];
                gn += *(const f32x4*)&Sg[ks][2][row][cg * 4];
            }
            if (role == 1) {
                // gi1 = partial + b_ih1 -> Gi slot t (f32, system-scope)
                const size_t gb =
                    ((size_t)t * BATCH + row) * G3 + ce;
                U128cast s0, s1, s2;
#pragma unroll
                for (int j = 0; j < 4; ++j) {
                    s0.v[j] = gr[j] + bh[0][j];
                    s1.v[j] = gz[j] + bh[1][j];
                    s2.v[j] = gn[j] + bh[2][j];
                }
                unsigned long long* p0 = (unsigned long long*)(Gi + gb);
                unsigned long long* p1 = (unsigned long long*)(Gi + gb + HID);
                unsigned long long* p2 = (unsigned long long*)(Gi + gb + 2 * HID);
                __hip_atomic_store(p0, s0.u[0], __ATOMIC_RELAXED, __HIP_MEMORY_SCOPE_SYSTEM);
                __hip_atomic_store(p0 + 1, s0.u[1], __ATOMIC_RELAXED, __HIP_MEMORY_SCOPE_SYSTEM);
                __hip_atomic_store(p1, s1.u[0], __ATOMIC_RELAXED, __HIP_MEMORY_SCOPE_SYSTEM);
                __hip_atomic_store(p1 + 1, s1.u[1], __ATOMIC_RELAXED, __HIP_MEMORY_SCOPE_SYSTEM);
                __hip_atomic_store(p2, s2.u[0], __ATOMIC_RELAXED, __HIP_MEMORY_SCOPE_SYSTEM);
                __hip_atomic_store(p2 + 1, s2.u[1], __ATOMIC_RELAXED, __HIP_MEMORY_SCOPE_SYSTEM);
            } else {
                U64cast hb4;
#pragma unroll
                for (int j = 0; j < 4; ++j) {
                    float rr = 1.f / (1.f + __expf(-(gi[i][0][j] + gr[j] + bh[0][j])));
                    float zz = 1.f / (1.f + __expf(-(gi[i][1][j] + gz[j] + bh[1][j])));
                    float nn = tanhf(gi[i][2][j] + rr * (gn[j] + bh[2][j]));
                    float h  = (1.f - zz) * nn + zz * hp[i][j];
                    hp[i][j] = h;
                    hb4.v[j] = (bf16_t)h;
                }
                bf16_t* dst = (role == 0 ? H0b : H1b) +
                              (size_t)t * BHID + (size_t)row * HID + ce;
                __hip_atomic_store((unsigned long long*)dst, hb4.u,
                                   __ATOMIC_RELAXED, __HIP_MEMORY_SCOPE_SYSTEM);
            }
        }

        // ---- publish (stores drained by syncthreads' vmcnt(0)) ----
        __syncthreads();
        if (tid == 0)
            __hip_atomic_store(&flags[role * 64 + cb], (unsigned)(t + 1),
                               __ATOMIC_RELAXED, __HIP_MEMORY_SCOPE_SYSTEM);
    }
}

// ---------------------------------------------------------------------------
extern "C" void kernel_launch(void* const* d_in, const int* in_sizes, int n_in,
                              void* d_out, int out_size, void* d_ws, size_t ws_size,
                              hipStream_t stream) {
    const int*   x        = (const int*)d_in[0];
    const float* enc_hid  = (const float*)d_in[2];   // [2,128,1024]
    const float* emb      = (const float*)d_in[3];
    const float* w_ih0    = (const float*)d_in[4];
    const float* w_hh0    = (const float*)d_in[5];
    const float* b_ih0    = (const float*)d_in[6];
    const float* b_hh0    = (const float*)d_in[7];
    const float* w_ih1    = (const float*)d_in[8];
    const float* w_hh1    = (const float*)d_in[9];
    const float* b_ih1    = (const float*)d_in[10];
    const float* b_hh1    = (const float*)d_in[11];
    const float* w_dec    = (const float*)d_in[12];
    const float* b_dec    = (const float*)d_in[13];
    float* out = (float*)d_out;

    char* ws = (char*)d_ws;
    size_t off = 0;
    auto alloc = [&](size_t bytes) {
        void* p = ws + off;
        off += (bytes + 255) & ~(size_t)255;
        return p;
    };
    unsigned* flags  = (unsigned*)alloc(1024);       // [0..63] L0, [64..127] G, [128..191] L1
    bf16_t* Xb     = (bf16_t*)alloc((size_t)MROWS * EMB * 2);
    bf16_t* Wih0b  = (bf16_t*)alloc((size_t)G3 * EMB * 2);
    bf16_t* Whh0b  = (bf16_t*)alloc((size_t)G3 * HID * 2);
    bf16_t* Wih1b  = (bf16_t*)alloc((size_t)G3 * HID * 2);
    bf16_t* Whh1b  = (bf16_t*)alloc((size_t)G3 * HID * 2);
    bf16_t* Wdecb  = (bf16_t*)alloc((size_t)VOC * HID * 2);
    bf16_t* h0ib   = (bf16_t*)alloc((size_t)BATCH * HID * 2);
    bf16_t* h1ib   = (bf16_t*)alloc((size_t)BATCH * HID * 2);
    float*  Gi     = (float*)alloc((size_t)MROWS * G3 * 4);
    bf16_t* H0b    = (bf16_t*)alloc((size_t)MROWS * HID * 2);
    bf16_t* H1b    = (bf16_t*)alloc((size_t)MROWS * HID * 2);

    hipMemsetAsync(flags, 0, 1024, stream);

    auto cvt = [&](const float* src, bf16_t* dst, int n) {
        int blocks = (n + 1023) / 1024;
        f32_to_bf16_kernel<<<blocks, 256, 0, stream>>>(src, dst, n);
    };

    cvt(w_ih0, Wih0b, G3 * EMB);
    cvt(w_hh0, Whh0b, G3 * HID);
    cvt(w_ih1, Wih1b, G3 * HID);
    cvt(w_hh1, Whh1b, G3 * HID);
    cvt(w_dec, Wdecb, VOC * HID);
    cvt(enc_hid, h0ib, BATCH * HID);
    cvt(enc_hid + BATCH * HID, h1ib, BATCH * HID);

    embed_kernel<<<MROWS, 128, 0, stream>>>(x, emb, Xb);

    // Gi0 = X @ w_ih0^T + b_ih0  -> [4096, 3072]
    gemm_bf16_kernel<1><<<dim3(G3 / 128, MROWS / 128), 256, 0, stream>>>(
        Xb, Wih0b, b_ih0, Gi, MROWS, G3, EMB);

    // fused dataflow scan: L0 + Gi1 + L1 in one launch
    fused_scan_kernel<<<192, 256, 0, stream>>>(
        h0ib, h1ib, enc_hid, Whh0b, Wih1b, Whh1b,
        b_hh0, b_ih1, b_hh1, Gi, H0b, H1b, flags);

    // logits = H1 @ w_dec^T + b_dec -> [4096, 32000]
    gemm256_bf16_kernel<1><<<dim3(VOC / 256, MROWS / 256), 512, 0, stream>>>(
        H1b, Wdecb, b_dec, out, MROWS, VOC, HID);
}